// Round 6
// baseline (274.569 us; speedup 1.0000x reference)
//
#include <hip/hip_runtime.h>
#include <hip/hip_bf16.h>

// I/O fp32; internal bf16 MFMA, fp32 accumulate (verified; absmax 1.6e-2).
// R8: split-kv attention (chunks of 1024), additive partials.
// R11: attn5 8-wave LDS-staged (verified, 248->215us).
// R12: counted vmcnt ring + XCD swizzle (gemm1 72->52.5us).
// R13: granule swizzle NULL (conflict counter = gload_lds DMA write
//      serialization, 393216 ops x 8 exactly; not read conflicts). Reverted.
// R14 (this round): gemm128 -> wave-private, BARRIER-FREE, LDS-FREE.
// Model: no pipe >40% busy at 52.5us => lock-step barrier convergence is
// the cost; A+B (14MB) is L2-resident so LDS staging buys nothing here.
// Each wave owns a 64x64 tile, loads its 8 fragments (16B/lane) straight
// from L2, reg-dbuf unroll-by-2 (named sets, rule #20). Epilogue unchanged.

typedef __attribute__((ext_vector_type(8))) short bf16x8;
typedef __attribute__((ext_vector_type(4))) float f32x4;

#define MFMA16(a, b, c) __builtin_amdgcn_mfma_f32_16x16x32_bf16(a, b, c, 0, 0, 0)

static constexpr int Bb = 2, Tt = 2048, Dd = 1024, Nn = 16, Hh = 64;
static constexpr float NEG_BIG = -30000.0f;
static constexpr float QSCALE  = 0.125f;

__device__ __forceinline__ short f2bf(float f) {
    __hip_bfloat16 h = __float2bfloat16(f);
    short s; __builtin_memcpy(&s, &h, 2); return s;
}
__device__ __forceinline__ float bf2f(short s) {
    __hip_bfloat16 h; __builtin_memcpy(&h, &s, 2); return __bfloat162float(h);
}
__device__ __forceinline__ bf16x8 cvt8(const float* __restrict__ p) {
    f32x4 a = *(const f32x4*)p, b = *(const f32x4*)(p + 4);
    bf16x8 r;
    #pragma unroll
    for (int j = 0; j < 4; ++j) { r[j] = f2bf(a[j]); r[4 + j] = f2bf(b[j]); }
    return r;
}
__device__ __forceinline__ bf16x8 cvt8s(const float* __restrict__ p, float s) {
    f32x4 a = *(const f32x4*)p, b = *(const f32x4*)(p + 4);
    bf16x8 r;
    #pragma unroll
    for (int j = 0; j < 4; ++j) { r[j] = f2bf(a[j] * s); r[4 + j] = f2bf(b[j] * s); }
    return r;
}

// async global->LDS, 16B per lane; lds base must be wave-uniform.
__device__ __forceinline__ void gload16(const short* g, short* l) {
    __builtin_amdgcn_global_load_lds(
        (const __attribute__((address_space(1))) unsigned int*)g,
        (__attribute__((address_space(3))) unsigned int*)l, 16, 0, 0);
}

template<int CTRL>
__device__ __forceinline__ float dppf(float x) {
    int i; __builtin_memcpy(&i, &x, 4);
    i = __builtin_amdgcn_update_dpp(0, i, CTRL, 0xf, 0xf, true);
    float r; __builtin_memcpy(&r, &i, 4); return r;
}
__device__ __forceinline__ float rowmax16(float x) {
    x = fmaxf(x, dppf<0x128>(x)); x = fmaxf(x, dppf<0x124>(x));
    x = fmaxf(x, dppf<0x122>(x)); x = fmaxf(x, dppf<0x121>(x));
    return x;
}
__device__ __forceinline__ float rowsum16(float x) {
    x += dppf<0x128>(x); x += dppf<0x124>(x);
    x += dppf<0x122>(x); x += dppf<0x121>(x);
    return x;
}

// ---------------- prep: x->bf16, w_attn/w_proj -> bf16 transposed [N][K] ---
__global__ __launch_bounds__(256) void prep(
    const float* __restrict__ x, const float* __restrict__ wa,
    const float* __restrict__ wp,
    short* __restrict__ xb, short* __restrict__ wat, short* __restrict__ wpt)
{
    const int bid = blockIdx.x, tid = threadIdx.x;
    if (bid < 1024) {
        __shared__ float s[64][65];
        const float* src; short* dst; int Nc, k0, n0;
        if (bid < 768) { src = wa; dst = wat; Nc = 3072; k0 = (bid & 15) * 64; n0 = (bid >> 4) * 64; }
        else { int b2 = bid - 768; src = wp; dst = wpt; Nc = 1024; k0 = (b2 & 15) * 64; n0 = (b2 >> 4) * 64; }
        const int row = tid >> 2, cg = (tid & 3) * 16;
        const float* p = src + (size_t)(k0 + row) * Nc + n0 + cg;
        #pragma unroll
        for (int i = 0; i < 4; ++i) {
            f32x4 v = *(const f32x4*)(p + 4 * i);
            #pragma unroll
            for (int j = 0; j < 4; ++j) s[row][cg + 4 * i + j] = v[j];
        }
        __syncthreads();
        bf16x8 o0, o1;
        #pragma unroll
        for (int j = 0; j < 8; ++j) { o0[j] = f2bf(s[cg + j][row]); o1[j] = f2bf(s[cg + 8 + j][row]); }
        short* q = dst + (size_t)(n0 + row) * 1024 + k0 + cg;
        *(bf16x8*)q = o0; *(bf16x8*)(q + 8) = o1;
    } else {
        const size_t base = (size_t)(bid - 1024) * 2048 + tid * 8;
        *(bf16x8*)(xb + base) = cvt8(x + base);
    }
}

// ------- 128x128 GEMM, bf16 A [M][K], bf16 Bt [N][K] ----------------------
// R14: wave-private 64x64 tiles, fragments direct from global (L2-resident
// operands), register double-buffer, NO LDS, NO barriers. XCD supertile
// swizzle kept (SN = 12 for MODE1, 4 for MODE2).
template<int MODE>
__global__ __launch_bounds__(256, 3) void gemm128(
    const short* __restrict__ A, const short* __restrict__ Bt,
    const float* __restrict__ bias,
    float* __restrict__ fk, float* __restrict__ fv,
    short* __restrict__ qb, short* __restrict__ kb, short* __restrict__ vt,
    float* __restrict__ fout, int K)
{
    const int tid = threadIdx.x, lane = tid & 63, wave = tid >> 6;
    const int l15 = lane & 15, quad = lane >> 4;

    // XCD supertile swizzle (bijective; consecutive lids round-robin XCDs)
    const int lid = (int)blockIdx.y * (int)gridDim.x + (int)blockIdx.x;
    const int xcd = lid & 7, sidx = lid >> 3;
    constexpr int SN = (MODE == 1) ? 12 : 4;          // supertile = 8m x SN n
    const int mt = (xcd & 3) * 8 + (sidx & 7);
    const int ntl = (xcd >> 2) * SN + (sidx >> 3);
    const int m0 = mt * 128, n0 = ntl * 128;

    const int wr = (wave >> 1) * 64, wc = (wave & 1) * 64;

    // fragment base pointers: row (m0+wr + i*16 + l15), col quad*8 within k-step
    const short* pa = A  + (size_t)(m0 + wr + l15) * K + quad * 8;
    const short* pb = Bt + (size_t)(n0 + wc + l15) * K + quad * 8;
    const size_t rstep = (size_t)16 * K;              // 16-row fragment stride

    f32x4 acc[4][4] = {};
    bf16x8 a0[4], b0[4], a1[4], b1[4];

    #pragma unroll
    for (int i = 0; i < 4; ++i) {
        a0[i] = *(const bf16x8*)(pa + (size_t)i * rstep);
        b0[i] = *(const bf16x8*)(pb + (size_t)i * rstep);
    }

    for (int k0 = 0; k0 < K; k0 += 64) {
        // issue odd-half loads (k0+32 < K always: K % 64 == 0)
        #pragma unroll
        for (int i = 0; i < 4; ++i) {
            a1[i] = *(const bf16x8*)(pa + (size_t)i * rstep + k0 + 32);
            b1[i] = *(const bf16x8*)(pb + (size_t)i * rstep + k0 + 32);
        }
        #pragma unroll
        for (int i = 0; i < 4; ++i)
        #pragma unroll
        for (int j = 0; j < 4; ++j)
            acc[i][j] = MFMA16(a0[i], b0[j], acc[i][j]);

        if (k0 + 64 < K) {
            #pragma unroll
            for (int i = 0; i < 4; ++i) {
                a0[i] = *(const bf16x8*)(pa + (size_t)i * rstep + k0 + 64);
                b0[i] = *(const bf16x8*)(pb + (size_t)i * rstep + k0 + 64);
            }
        }
        #pragma unroll
        for (int i = 0; i < 4; ++i)
        #pragma unroll
        for (int j = 0; j < 4; ++j)
            acc[i][j] = MFMA16(a1[i], b1[j], acc[i][j]);
    }

    #pragma unroll
    for (int mt2 = 0; mt2 < 4; ++mt2)
    #pragma unroll
    for (int nt2 = 0; nt2 < 4; ++nt2) {
        const int gc = n0 + wc + nt2 * 16 + l15;
        const float bv = bias[gc];
        #pragma unroll
        for (int r = 0; r < 4; ++r) {
            const int grow = m0 + wr + mt2 * 16 + quad * 4 + r;
            const float val = acc[mt2][nt2][r] + bv;
            if (MODE == 1) {
                const int reg = gc >> 10, c = gc & 1023;
                if (reg == 0) {
                    qb[(size_t)grow * 1024 + c] = f2bf(val * QSCALE);
                } else {
                    const int bidx = grow >> 11, tt = grow & 2047;
                    const int nh = c >> 6, h = c & 63;
                    if (reg == 1) {
                        fk[(size_t)grow * 1024 + c] = val;
                        kb[((size_t)(bidx * Nn + nh) * Tt + tt) * Hh + h] = f2bf(val);
                    } else {
                        fv[(size_t)grow * 1024 + c] = val;
                        vt[((size_t)(bidx * Nn + nh) * Hh + h) * Tt + tt] = f2bf(val);
                    }
                }
            } else {
                fout[(size_t)grow * 1024 + gc] = val;
            }
        }
    }
}

// ---- attention v5: 8 waves x 16 q-rows, LDS-staged K/V (swizzled), dbuf ---
__global__ __launch_bounds__(512, 6) void attn5(
    const short* __restrict__ Qb, const short* __restrict__ Kb,
    const short* __restrict__ Vt,
    short* __restrict__ op_part, float* __restrict__ ls_part)
{
    const int by = 15 - (int)blockIdx.y;          // heavy blocks first
    const int c  = blockIdx.z;
    if (c && by < 8) return;                      // chunk 1 only for by>=8

    __shared__ short sK[2][64][64];               // [t'][h], XOR-swizzled storage
    __shared__ short sV[2][64][64];               // [h][t'], XOR-swizzled storage
    __shared__ short sP[8][16][72];

    const int tid = threadIdx.x, lane = tid & 63, wave = tid >> 6;  // 8 waves
    const int l15 = lane & 15, quad = lane >> 4;
    const int head = blockIdx.x;                  // b*16+n
    const int b = head >> 4, n = head & 15;
    const int q0w = by * 128 + wave * 16;         // this wave's 16 q-rows

    const int gmask = (q0w + 15) >> 6;            // this wave's masked-tile index
    const int g0 = c * 16;
    const int ntmax = min(16, 2 * by + 2 - g0);   // block-uniform tile count

    const size_t kvhead = (size_t)head * Tt * Hh;
    const short* kbh = Kb + kvhead;
    const short* vth = Vt + kvhead;

    // Q fragment (rows q0w..q0w+15)
    const short* qp = Qb + ((size_t)b * Tt + q0w + l15) * Dd + n * Hh + quad * 8;
    const bf16x8 qf0 = *(const bf16x8*)qp;
    const bf16x8 qf1 = *(const bf16x8*)(qp + 32);

    // staging map: wave stages rows [wave*8, wave*8+8) of each 64x64 tile.
    // storage[row][blk] holds logical[row][blk ^ (row&7)]  (blk = 16B block).
    const int sr   = wave * 8 + (lane >> 3);            // tile row
    const int srcb = (((lane & 7) ^ (lane >> 3))) * 8;  // inverse-swizzled src col (shorts)
    const int swz  = l15 & 7;
    const int bsw  = quad ^ swz;                        // storage blk for logical blk quad

    f32x4 o_acc[4] = {};
    float lsum[4] = {};

#define STAGE_KV(bb, ktb)                                               \
    do {                                                                \
        gload16(kbh + (size_t)((ktb) + sr) * Hh + srcb, &sK[bb][wave * 8][0]); \
        gload16(vth + (size_t)sr * Tt + (ktb) + srcb,   &sV[bb][wave * 8][0]); \
    } while (0)

    STAGE_KV(0, g0 * 64);
    __syncthreads();

    int buf = 0;
    for (int it = 0; it < ntmax; ++it) {
        const int kt = (g0 + it) * 64;
        if (it + 1 < ntmax) STAGE_KV(buf ^ 1, kt + 64);

        // QK^T: K fragments from swizzled LDS, j-pairs to bound VGPR
        f32x4 s[4] = {};
        #pragma unroll
        for (int jp = 0; jp < 2; ++jp) {
            bf16x8 ka0 = *(const bf16x8*)&sK[buf][32 * jp      + l15][bsw * 8];
            bf16x8 kc0 = *(const bf16x8*)&sK[buf][32 * jp      + l15][(bsw ^ 4) * 8];
            bf16x8 ka1 = *(const bf16x8*)&sK[buf][32 * jp + 16 + l15][bsw * 8];
            bf16x8 kc1 = *(const bf16x8*)&sK[buf][32 * jp + 16 + l15][(bsw ^ 4) * 8];
            __builtin_amdgcn_s_setprio(1);
            s[2 * jp]     = MFMA16(qf0, ka0, s[2 * jp]);
            s[2 * jp]     = MFMA16(qf1, kc0, s[2 * jp]);
            s[2 * jp + 1] = MFMA16(qf0, ka1, s[2 * jp + 1]);
            s[2 * jp + 1] = MFMA16(qf1, kc1, s[2 * jp + 1]);
            __builtin_amdgcn_s_setprio(0);
        }

        // softmax (fixed max; tiles past gmask fully masked -> exp = 0 exactly)
        const bool masked = (g0 + it >= gmask);
        #pragma unroll
        for (int r = 0; r < 4; ++r) {
            const int row = q0w + quad * 4 + r;
            float x0 = s[0][r], x1 = s[1][r], x2 = s[2][r], x3 = s[3][r];
            if (masked) {
                if (kt + l15      > row) x0 = NEG_BIG;
                if (kt + 16 + l15 > row) x1 = NEG_BIG;
                if (kt + 32 + l15 > row) x2 = NEG_BIG;
                if (kt + 48 + l15 > row) x3 = NEG_BIG;
            }
            const float p0 = __expf(x0), p1 = __expf(x1);
            const float p2 = __expf(x2), p3 = __expf(x3);
            lsum[r] += (p0 + p1) + (p2 + p3);
            short* pw = &sP[wave][quad * 4 + r][l15];
            pw[0] = f2bf(p0); pw[16] = f2bf(p1); pw[32] = f2bf(p2); pw[48] = f2bf(p3);
        }
        __asm__ volatile("s_waitcnt lgkmcnt(0)" ::: "memory");
        bf16x8 pf0 = *(const bf16x8*)&sP[wave][l15][quad * 8];
        bf16x8 pf1 = *(const bf16x8*)&sP[wave][l15][32 + quad * 8];
        #pragma unroll
        for (int hc = 0; hc < 4; ++hc) {
            bf16x8 v0 = *(const bf16x8*)&sV[buf][hc * 16 + l15][bsw * 8];
            bf16x8 v1 = *(const bf16x8*)&sV[buf][hc * 16 + l15][(bsw ^ 4) * 8];
            __builtin_amdgcn_s_setprio(1);
            o_acc[hc] = MFMA16(pf0, v0, o_acc[hc]);
            o_acc[hc] = MFMA16(pf1, v1, o_acc[hc]);
            __builtin_amdgcn_s_setprio(0);
        }
        __syncthreads();   // drains stage loads for buf^1; all reads of buf done
        buf ^= 1;
    }
#undef STAGE_KV

    // write partials (slot bijective over active (by,c): by<8 -> by ; else 2by-8+c)
    const int slot = head * 24 + (by < 8 ? by : 2 * by - 8 + c);
    short* opw = op_part + ((size_t)slot * 128 + wave * 16) * 64;
    #pragma unroll
    for (int r = 0; r < 4; ++r) {
        const float l = rowsum16(lsum[r]);
        const int rloc = quad * 4 + r;
        if (l15 == 0) ls_part[slot * 128 + wave * 16 + rloc] = l;
        #pragma unroll
        for (int hc = 0; hc < 4; ++hc)
            opw[rloc * 64 + hc * 16 + l15] = f2bf(o_acc[hc][r]);
    }
}

// ---- merge partials + normalize -> Ob bf16 [b][t][n*64+h] ----
__global__ __launch_bounds__(256) void attn_reduce(
    const short* __restrict__ op_part, const float* __restrict__ ls_part,
    short* __restrict__ Ob)
{
    const int idx = blockIdx.x * 256 + threadIdx.x;   // 524288 threads
    const int r = idx >> 3;                            // row 0..65535 (head*2048+t)
    const int h0 = (idx & 7) * 8;
    const int head = r >> 11, t = r & 2047;
    const int by = t >> 7, tr = t & 127;
    const int nch = 1 + (by >= 8);
    const int base = head * 24 + (by < 8 ? by : 2 * by - 8);

    float acc[8] = {};
    float l = 0.f;
    for (int c = 0; c < nch; ++c) {
        const int slot = base + c;
        bf16x8 v = *(const bf16x8*)(op_part + ((size_t)slot * 128 + tr) * 64 + h0);
        #pragma unroll
        for (int j = 0; j < 8; ++j) acc[j] += bf2f(v[j]);
        l += ls_part[slot * 128 + tr];
    }
    const float rl = 1.0f / fmaxf(l, 1e-20f);
    bf16x8 o;
    #pragma unroll
    for (int j = 0; j < 8; ++j) o[j] = f2bf(acc[j] * rl);
    const int b = head >> 4, n = head & 15;
    *(bf16x8*)(Ob + ((size_t)(b * Tt + t)) * Dd + n * Hh + h0) = o;
}

// ======================= fallback kernels (verified R4/R5) =================
__global__ __launch_bounds__(256) void gemm_bias_split(
    const float* __restrict__ A, const float* __restrict__ Bm,
    const float* __restrict__ bias,
    float* __restrict__ dst0, float* __restrict__ dst1, float* __restrict__ dst2,
    short* __restrict__ kb, short* __restrict__ vt,
    int K, int Ncols, int Dsplit)
{
    __shared__ short sA[64][40];
    __shared__ short sBt[64][40];
    const int tid  = threadIdx.x;
    const int lane = tid & 63;
    const int wave = tid >> 6;
    const int l15  = lane & 15;
    const int quad = lane >> 4;
    const int m0 = blockIdx.x * 64;
    const int n0 = blockIdx.y * 64;
    const int wm = (wave >> 1) * 32;
    const int wn = (wave & 1) * 32;
    const int ar = tid >> 2, ac = (tid & 3) * 8;
    const int bk = tid >> 3, bc = (tid & 7) * 8;

    f32x4 acc[2][2] = {};
    for (int k0 = 0; k0 < K; k0 += 32) {
        bf16x8 av = cvt8(A  + (size_t)(m0 + ar) * K     + k0 + ac);
        bf16x8 bv = cvt8(Bm + (size_t)(k0 + bk) * Ncols + n0 + bc);
        *(bf16x8*)&sA[ar][ac] = av;
        #pragma unroll
        for (int j = 0; j < 8; ++j) sBt[bc + j][bk] = bv[j];
        __syncthreads();
        bf16x8 a0 = *(const bf16x8*)&sA[wm + l15][quad * 8];
        bf16x8 a1 = *(const bf16x8*)&sA[wm + 16 + l15][quad * 8];
        bf16x8 b0 = *(const bf16x8*)&sBt[wn + l15][quad * 8];
        bf16x8 b1 = *(const bf16x8*)&sBt[wn + 16 + l15][quad * 8];
        acc[0][0] = MFMA16(a0, b0, acc[0][0]);
        acc[0][1] = MFMA16(a0, b1, acc[0][1]);
        acc[1][0] = MFMA16(a1, b0, acc[1][0]);
        acc[1][1] = MFMA16(a1, b1, acc[1][1]);
        __syncthreads();
    }
    #pragma unroll
    for (int i = 0; i < 2; ++i)
    #pragma unroll
    for (int j = 0; j < 2; ++j) {
        const int ncol = n0 + wn + j * 16 + l15;
        const float bvf = bias[ncol];
        float* dbase; int c, which;
        if (ncol < Dsplit)        { dbase = dst0; c = ncol;            which = 0; }
        else if (ncol < 2*Dsplit) { dbase = dst1; c = ncol - Dsplit;   which = 1; }
        else                      { dbase = dst2; c = ncol - 2*Dsplit; which = 2; }
        const int nh = c >> 6, h = c & 63;
        #pragma unroll
        for (int r = 0; r < 4; ++r) {
            const int mrow = m0 + wm + i * 16 + quad * 4 + r;
            const float val = acc[i][j][r] + bvf;
            dbase[(size_t)mrow * Dsplit + c] = val;
            if (which == 1 && kb) {
                const int bidx = mrow >> 11, tt = mrow & 2047;
                kb[((size_t)(bidx * Nn + nh) * Tt + tt) * Hh + h] = f2bf(val);
            } else if (which == 2 && vt) {
                const int bidx = mrow >> 11, tt = mrow & 2047;
                vt[((size_t)(bidx * Nn + nh) * Hh + h) * Tt + tt] = f2bf(val);
            }
        }
    }
}

__global__ __launch_bounds__(256) void attn_fast(
    const float* __restrict__ Q, const short* __restrict__ Kb,
    const short* __restrict__ Vt, float* __restrict__ O)
{
    __shared__ short sP[4][2][16][40];
    const int tid  = threadIdx.x;
    const int lane = tid & 63;
    const int wave = tid >> 6;
    const int l15  = lane & 15;
    const int quad = lane >> 4;
    const int b = blockIdx.x >> 4, n = blockIdx.x & 15;
    const int qg = ((int)gridDim.y - 1 - (int)blockIdx.y) * 4 + wave;
    const int q0 = qg * 16;

    const size_t ohead  = (size_t)b * Tt * Dd + (size_t)n * Hh;
    const size_t kvhead = (size_t)(b * Nn + n) * Tt * Hh;
    const short* kbh = Kb + kvhead;
    const short* vth = Vt + kvhead;

    const float* qrow = Q + ohead + (size_t)(q0 + l15) * Dd;
    const bf16x8 qf0 = cvt8s(qrow + quad * 8, QSCALE);
    const bf16x8 qf1 = cvt8s(qrow + 32 + quad * 8, QSCALE);

    float m_i[4], l_i[4];
    f32x4 o_acc[4] = {};
    #pragma unroll
    for (int r = 0; r < 4; ++r) { m_i[r] = NEG_BIG; l_i[r] = 0.f; }

    int par = 0;
    for (int kt = 0; kt < q0 + 16; kt += 32, par ^= 1) {
        f32x4 s0 = {}, s1 = {};
        {
            const short* k0 = kbh + (size_t)(kt + l15) * Hh + quad * 8;
            bf16x8 k0a = *(const bf16x8*)k0;
            bf16x8 k0b = *(const bf16x8*)(k0 + 32);
            const short* k1 = k0 + 16 * Hh;
            bf16x8 k1a = *(const bf16x8*)k1;
            bf16x8 k1b = *(const bf16x8*)(k1 + 32);
            s0 = MFMA16(qf0, k0a, s0); s0 = MFMA16(qf1, k0b, s0);
            s1 = MFMA16(qf0, k1a, s1); s1 = MFMA16(qf1, k1b, s1);
        }
        const int qr0 = q0 + quad * 4;
        #pragma unroll
        for (int r = 0; r < 4; ++r) {
            float x0 = (kt + l15      > qr0 + r) ? NEG_BIG : s0[r];
            float x1 = (kt + 16 + l15 > qr0 + r) ? NEG_BIG : s1[r];
            const float t  = rowmax16(fmaxf(x0, x1));
            const float mn = fmaxf(m_i[r], t);
            const float alpha = __expf(m_i[r] - mn);
            const float p0 = __expf(x0 - mn);
            const float p1 = __expf(x1 - mn);
            l_i[r] = l_i[r] * alpha + rowsum16(p0 + p1);
            m_i[r] = mn;
            #pragma unroll
            for (int hc = 0; hc < 4; ++hc) o_acc[hc][r] *= alpha;
            sP[wave][par][quad * 4 + r][l15]      = f2bf(p0);
            sP[wave][par][quad * 4 + r][16 + l15] = f2bf(p1);
        }
        __asm__ volatile("s_waitcnt lgkmcnt(0)" ::: "memory");
        bf16x8 pf = *(const bf16x8*)&sP[wave][par][l15][quad * 8];
        #pragma unroll
        for (int hc = 0; hc < 4; ++hc) {
            bf16x8 vf = *(const bf16x8*)(vth + (size_t)(hc * 16 + l15) * Tt + kt + quad * 8);
            o_acc[hc] = MFMA16(pf, vf, o_acc[hc]);
        }
    }
    #pragma unroll
    for (int r = 0; r < 4; ++r) {
        const float rl = 1.0f / fmaxf(l_i[r], 1e-20f);
        #pragma unroll
        for (int hc = 0; hc < 4; ++hc)
            O[ohead + (size_t)(q0 + quad * 4 + r) * Dd + hc * 16 + l15] = o_acc[hc][r] * rl;
    }
}

extern "C" void kernel_launch(void* const* d_in, const int* in_sizes, int n_in,
                              void* d_out, int out_size, void* d_ws, size_t ws_size,
                              hipStream_t stream) {
    const float* x      = (const float*)d_in[0];
    const float* w_attn = (const float*)d_in[1];
    const float* b_attn = (const float*)d_in[2];
    const float* w_proj = (const float*)d_in[3];
    const float* b_proj = (const float*)d_in[4];

    const size_t elems = (size_t)Bb * Tt * Dd;      // 4,194,304
    float* out  = (float*)d_out;
    float* kout = out  + elems;
    float* vout = kout + elems;

    // v2 ws layout (shorts): qb, kb, vt, wpt(1M), xb(=ob after gemm1), op_part(768 slots), ls_part
    const size_t NSLOT = (size_t)32 * 24;           // 768
    const size_t need_v2 = (4 * elems + (size_t)1024 * 1024 + NSLOT * 128 * 64) * 2
                         + NSLOT * 128 * 4;         // ~48.6 MB

    if (ws_size >= need_v2) {
        short* qb  = (short*)d_ws;
        short* kb  = qb + elems;
        short* vt  = kb + elems;
        short* wpt = vt + elems;
        short* xb  = wpt + (size_t)1024 * 1024;     // dead after gemm1
        short* ob  = xb;                            // reuse for attn output
        short* op_part = xb + elems;                // 768*128*64 shorts
        float* ls_part = (float*)(op_part + NSLOT * 128 * 64);
        // wat lives where op_part starts (dead after gemm1)
        short* wat = op_part;

        prep<<<3072, 256, 0, stream>>>(x, w_attn, w_proj, xb, wat, wpt);
        gemm128<1><<<dim3(32, 24), 256, 0, stream>>>(
            xb, wat, b_attn, kout, vout, qb, kb, vt, nullptr, Dd);
        attn5<<<dim3(Bb * Nn, 16, 2), 512, 0, stream>>>(qb, kb, vt, op_part, ls_part);
        attn_reduce<<<2048, 256, 0, stream>>>(op_part, ls_part, ob);
        gemm128<2><<<dim3(32, 8), 256, 0, stream>>>(
            ob, wpt, b_proj, nullptr, nullptr, nullptr, nullptr, nullptr, out, Dd);
    } else {
        // fallback (verified R4 path): needs 32 MB ws
        float* o_ws = (float*)d_ws;
        short* kb = (short*)((char*)d_ws + elems * 4);
        short* vt = kb + elems;
        gemm_bias_split<<<dim3((Bb * Tt) / 64, (3 * Dd) / 64), 256, 0, stream>>>(
            x, w_attn, b_attn, out, kout, vout, kb, vt, Dd, 3 * Dd, Dd);
        attn_fast<<<dim3(Bb * Nn, Tt / 64), 256, 0, stream>>>(out, kb, vt, o_ws);
        gemm_bias_split<<<dim3((Bb * Tt) / 64, Dd / 64), 256, 0, stream>>>(
            o_ws, w_proj, b_proj, out, out, out, nullptr, nullptr, Dd, Dd, Dd);
    }
}

// Round 7
// 200.501 us; speedup vs baseline: 1.3694x; 1.3694x over previous
//
#include <hip/hip_runtime.h>
#include <hip/hip_bf16.h>

// I/O fp32; internal bf16 MFMA, fp32 accumulate (verified; absmax 1.6e-2).
// R8: split-kv attention (chunks of 1024), additive partials.
// R11: attn5 8-wave LDS-staged (verified, 248->215us).
// R12: counted vmcnt ring + XCD swizzle (gemm1 72->52.5us, total 202.2).
// R13: granule swizzle NULL. R14: LDS-free gemm REGRESSED 2.1x (fragment
// loads at (row+l15)*K are a 16-line gather per wave-load; staging exists
// to COALESCE, not just to cache). Reverted.
// R15 (this round): gemm = exact R12 structure; MODE2 gets 128x64 tiles
// (grid 32x16 = 512 blocks = 2/CU, was 1/CU with zero cross-block overlap).
// Per-wave stage = 3 loads => vmcnt(3); bijective 8mx8n supertile swizzle.

typedef __attribute__((ext_vector_type(8))) short bf16x8;
typedef __attribute__((ext_vector_type(4))) float f32x4;

#define MFMA16(a, b, c) __builtin_amdgcn_mfma_f32_16x16x32_bf16(a, b, c, 0, 0, 0)

static constexpr int Bb = 2, Tt = 2048, Dd = 1024, Nn = 16, Hh = 64;
static constexpr float NEG_BIG = -30000.0f;
static constexpr float QSCALE  = 0.125f;

__device__ __forceinline__ short f2bf(float f) {
    __hip_bfloat16 h = __float2bfloat16(f);
    short s; __builtin_memcpy(&s, &h, 2); return s;
}
__device__ __forceinline__ float bf2f(short s) {
    __hip_bfloat16 h; __builtin_memcpy(&h, &s, 2); return __bfloat162float(h);
}
__device__ __forceinline__ bf16x8 cvt8(const float* __restrict__ p) {
    f32x4 a = *(const f32x4*)p, b = *(const f32x4*)(p + 4);
    bf16x8 r;
    #pragma unroll
    for (int j = 0; j < 4; ++j) { r[j] = f2bf(a[j]); r[4 + j] = f2bf(b[j]); }
    return r;
}
__device__ __forceinline__ bf16x8 cvt8s(const float* __restrict__ p, float s) {
    f32x4 a = *(const f32x4*)p, b = *(const f32x4*)(p + 4);
    bf16x8 r;
    #pragma unroll
    for (int j = 0; j < 4; ++j) { r[j] = f2bf(a[j] * s); r[4 + j] = f2bf(b[j] * s); }
    return r;
}

// async global->LDS, 16B per lane; lds base must be wave-uniform.
__device__ __forceinline__ void gload16(const short* g, short* l) {
    __builtin_amdgcn_global_load_lds(
        (const __attribute__((address_space(1))) unsigned int*)g,
        (__attribute__((address_space(3))) unsigned int*)l, 16, 0, 0);
}

template<int CTRL>
__device__ __forceinline__ float dppf(float x) {
    int i; __builtin_memcpy(&i, &x, 4);
    i = __builtin_amdgcn_update_dpp(0, i, CTRL, 0xf, 0xf, true);
    float r; __builtin_memcpy(&r, &i, 4); return r;
}
__device__ __forceinline__ float rowmax16(float x) {
    x = fmaxf(x, dppf<0x128>(x)); x = fmaxf(x, dppf<0x124>(x));
    x = fmaxf(x, dppf<0x122>(x)); x = fmaxf(x, dppf<0x121>(x));
    return x;
}
__device__ __forceinline__ float rowsum16(float x) {
    x += dppf<0x128>(x); x += dppf<0x124>(x);
    x += dppf<0x122>(x); x += dppf<0x121>(x);
    return x;
}

// ---------------- prep: x->bf16, w_attn/w_proj -> bf16 transposed [N][K] ---
__global__ __launch_bounds__(256) void prep(
    const float* __restrict__ x, const float* __restrict__ wa,
    const float* __restrict__ wp,
    short* __restrict__ xb, short* __restrict__ wat, short* __restrict__ wpt)
{
    const int bid = blockIdx.x, tid = threadIdx.x;
    if (bid < 1024) {
        __shared__ float s[64][65];
        const float* src; short* dst; int Nc, k0, n0;
        if (bid < 768) { src = wa; dst = wat; Nc = 3072; k0 = (bid & 15) * 64; n0 = (bid >> 4) * 64; }
        else { int b2 = bid - 768; src = wp; dst = wpt; Nc = 1024; k0 = (b2 & 15) * 64; n0 = (b2 >> 4) * 64; }
        const int row = tid >> 2, cg = (tid & 3) * 16;
        const float* p = src + (size_t)(k0 + row) * Nc + n0 + cg;
        #pragma unroll
        for (int i = 0; i < 4; ++i) {
            f32x4 v = *(const f32x4*)(p + 4 * i);
            #pragma unroll
            for (int j = 0; j < 4; ++j) s[row][cg + 4 * i + j] = v[j];
        }
        __syncthreads();
        bf16x8 o0, o1;
        #pragma unroll
        for (int j = 0; j < 8; ++j) { o0[j] = f2bf(s[cg + j][row]); o1[j] = f2bf(s[cg + 8 + j][row]); }
        short* q = dst + (size_t)(n0 + row) * 1024 + k0 + cg;
        *(bf16x8*)q = o0; *(bf16x8*)(q + 8) = o1;
    } else {
        const size_t base = (size_t)(bid - 1024) * 2048 + tid * 8;
        *(bf16x8*)(xb + base) = cvt8(x + base);
    }
}

// ------- 128xBN GEMM, bf16 A [M][K], bf16 Bt [N][K] -----------------------
// R12 structure: 3-buffer ring, stage-ahead-2, counted vmcnt, raw s_barrier,
// XCD supertile swizzle. R15: BN=128 (MODE1, grid 32x24) / BN=64 (MODE2,
// grid 32x16 = 2 blocks/CU).
template<int MODE>
__global__ __launch_bounds__(256) void gemm128(
    const short* __restrict__ A, const short* __restrict__ Bt,
    const float* __restrict__ bias,
    float* __restrict__ fk, float* __restrict__ fv,
    short* __restrict__ qb, short* __restrict__ kb, short* __restrict__ vt,
    float* __restrict__ fout, int K)
{
    constexpr int BN = (MODE == 1) ? 128 : 64;        // n-tile width
    constexpr int NF = BN / 32;                       // n-frags per wave (4|2)
    __shared__ short sA[3][128][32];
    __shared__ short sB[3][BN][32];
    const int tid = threadIdx.x, lane = tid & 63, wave = tid >> 6;
    const int l15 = lane & 15, quad = lane >> 4;

    // XCD supertile swizzle (bijective; consecutive lids round-robin XCDs)
    const int lid = (int)blockIdx.y * (int)gridDim.x + (int)blockIdx.x;
    const int xcd = lid & 7, sidx = lid >> 3;
    constexpr int SN = (MODE == 1) ? 12 : 8;          // supertile = 8m x SN n
    const int mt = (xcd & 3) * 8 + (sidx & 7);
    const int ntl = (xcd >> 2) * SN + (sidx >> 3);
    const int m0 = mt * 128, n0 = ntl * BN;

    const int wr = (wave >> 1) * 64, wc = (wave & 1) * (BN / 2);

    // staging source mapping: lane l covers row base+l/4, col shorts (l%4)*8
    const int rl  = lane >> 2;
    const int csh = (lane & 3) * 8;
    const size_t aOff0 = (size_t)(m0 + wave * 16 + rl) * K + csh;
    const size_t aOff1 = aOff0 + (size_t)64 * K;
    const size_t bOff0 = (size_t)(n0 + wave * 16 + rl) * K + csh;
    const size_t bOff1 = bOff0 + (size_t)64 * K;      // used only if BN==128

    f32x4 acc[4][NF] = {};

#define STAGE_G(pp, kk)                                                \
    do {                                                               \
        gload16(A  + aOff0 + (kk), &sA[pp][wave * 16][0]);             \
        gload16(A  + aOff1 + (kk), &sA[pp][64 + wave * 16][0]);        \
        gload16(Bt + bOff0 + (kk), &sB[pp][wave * 16][0]);             \
        if constexpr (BN == 128)                                       \
            gload16(Bt + bOff1 + (kk), &sB[pp][64 + wave * 16][0]);    \
    } while (0)

    // prologue: tiles 0 and 1 in flight (K >= 64 always here)
    STAGE_G(0, 0);
    STAGE_G(1, 32);

    int cur = 0;
    for (int k0 = 0; k0 < K; k0 += 32) {
        // tile `cur` guaranteed landed: only the NEXT tile's loads may remain
        if (k0 + 32 < K) {
            if constexpr (MODE == 1) asm volatile("s_waitcnt vmcnt(4)" ::: "memory");
            else                     asm volatile("s_waitcnt vmcnt(3)" ::: "memory");
        } else {
            asm volatile("s_waitcnt vmcnt(0)" ::: "memory");
        }
        __builtin_amdgcn_s_barrier();
        __builtin_amdgcn_sched_barrier(0);

        const int nxt2 = cur >= 1 ? cur - 1 : cur + 2;   // (cur+2)%3
        if (k0 + 64 < K) STAGE_G(nxt2, k0 + 64);

        bf16x8 af[4], bfr[NF];
        #pragma unroll
        for (int mt2 = 0; mt2 < 4; ++mt2) af[mt2]  = *(const bf16x8*)&sA[cur][wr + mt2 * 16 + l15][quad * 8];
        #pragma unroll
        for (int nt2 = 0; nt2 < NF; ++nt2) bfr[nt2] = *(const bf16x8*)&sB[cur][wc + nt2 * 16 + l15][quad * 8];
        #pragma unroll
        for (int mt2 = 0; mt2 < 4; ++mt2)
        #pragma unroll
        for (int nt2 = 0; nt2 < NF; ++nt2)
            acc[mt2][nt2] = MFMA16(af[mt2], bfr[nt2], acc[mt2][nt2]);

        cur = cur < 2 ? cur + 1 : 0;
    }
#undef STAGE_G

    #pragma unroll
    for (int mt2 = 0; mt2 < 4; ++mt2)
    #pragma unroll
    for (int nt2 = 0; nt2 < NF; ++nt2) {
        const int gc = n0 + wc + nt2 * 16 + l15;
        const float bv = bias[gc];
        #pragma unroll
        for (int r = 0; r < 4; ++r) {
            const int grow = m0 + wr + mt2 * 16 + quad * 4 + r;
            const float val = acc[mt2][nt2][r] + bv;
            if (MODE == 1) {
                const int reg = gc >> 10, c = gc & 1023;
                if (reg == 0) {
                    qb[(size_t)grow * 1024 + c] = f2bf(val * QSCALE);
                } else {
                    const int bidx = grow >> 11, tt = grow & 2047;
                    const int nh = c >> 6, h = c & 63;
                    if (reg == 1) {
                        fk[(size_t)grow * 1024 + c] = val;
                        kb[((size_t)(bidx * Nn + nh) * Tt + tt) * Hh + h] = f2bf(val);
                    } else {
                        fv[(size_t)grow * 1024 + c] = val;
                        vt[((size_t)(bidx * Nn + nh) * Hh + h) * Tt + tt] = f2bf(val);
                    }
                }
            } else {
                fout[(size_t)grow * 1024 + gc] = val;
            }
        }
    }
}

// ---- attention v5: 8 waves x 16 q-rows, LDS-staged K/V (swizzled), dbuf ---
__global__ __launch_bounds__(512, 6) void attn5(
    const short* __restrict__ Qb, const short* __restrict__ Kb,
    const short* __restrict__ Vt,
    short* __restrict__ op_part, float* __restrict__ ls_part)
{
    const int by = 15 - (int)blockIdx.y;          // heavy blocks first
    const int c  = blockIdx.z;
    if (c && by < 8) return;                      // chunk 1 only for by>=8

    __shared__ short sK[2][64][64];               // [t'][h], XOR-swizzled storage
    __shared__ short sV[2][64][64];               // [h][t'], XOR-swizzled storage
    __shared__ short sP[8][16][72];

    const int tid = threadIdx.x, lane = tid & 63, wave = tid >> 6;  // 8 waves
    const int l15 = lane & 15, quad = lane >> 4;
    const int head = blockIdx.x;                  // b*16+n
    const int b = head >> 4, n = head & 15;
    const int q0w = by * 128 + wave * 16;         // this wave's 16 q-rows

    const int gmask = (q0w + 15) >> 6;            // this wave's masked-tile index
    const int g0 = c * 16;
    const int ntmax = min(16, 2 * by + 2 - g0);   // block-uniform tile count

    const size_t kvhead = (size_t)head * Tt * Hh;
    const short* kbh = Kb + kvhead;
    const short* vth = Vt + kvhead;

    // Q fragment (rows q0w..q0w+15)
    const short* qp = Qb + ((size_t)b * Tt + q0w + l15) * Dd + n * Hh + quad * 8;
    const bf16x8 qf0 = *(const bf16x8*)qp;
    const bf16x8 qf1 = *(const bf16x8*)(qp + 32);

    // staging map: wave stages rows [wave*8, wave*8+8) of each 64x64 tile.
    // storage[row][blk] holds logical[row][blk ^ (row&7)]  (blk = 16B block).
    const int sr   = wave * 8 + (lane >> 3);            // tile row
    const int srcb = (((lane & 7) ^ (lane >> 3))) * 8;  // inverse-swizzled src col (shorts)
    const int swz  = l15 & 7;
    const int bsw  = quad ^ swz;                        // storage blk for logical blk quad

    f32x4 o_acc[4] = {};
    float lsum[4] = {};

#define STAGE_KV(bb, ktb)                                               \
    do {                                                                \
        gload16(kbh + (size_t)((ktb) + sr) * Hh + srcb, &sK[bb][wave * 8][0]); \
        gload16(vth + (size_t)sr * Tt + (ktb) + srcb,   &sV[bb][wave * 8][0]); \
    } while (0)

    STAGE_KV(0, g0 * 64);
    __syncthreads();

    int buf = 0;
    for (int it = 0; it < ntmax; ++it) {
        const int kt = (g0 + it) * 64;
        if (it + 1 < ntmax) STAGE_KV(buf ^ 1, kt + 64);

        // QK^T: K fragments from swizzled LDS, j-pairs to bound VGPR
        f32x4 s[4] = {};
        #pragma unroll
        for (int jp = 0; jp < 2; ++jp) {
            bf16x8 ka0 = *(const bf16x8*)&sK[buf][32 * jp      + l15][bsw * 8];
            bf16x8 kc0 = *(const bf16x8*)&sK[buf][32 * jp      + l15][(bsw ^ 4) * 8];
            bf16x8 ka1 = *(const bf16x8*)&sK[buf][32 * jp + 16 + l15][bsw * 8];
            bf16x8 kc1 = *(const bf16x8*)&sK[buf][32 * jp + 16 + l15][(bsw ^ 4) * 8];
            __builtin_amdgcn_s_setprio(1);
            s[2 * jp]     = MFMA16(qf0, ka0, s[2 * jp]);
            s[2 * jp]     = MFMA16(qf1, kc0, s[2 * jp]);
            s[2 * jp + 1] = MFMA16(qf0, ka1, s[2 * jp + 1]);
            s[2 * jp + 1] = MFMA16(qf1, kc1, s[2 * jp + 1]);
            __builtin_amdgcn_s_setprio(0);
        }

        // softmax (fixed max; tiles past gmask fully masked -> exp = 0 exactly)
        const bool masked = (g0 + it >= gmask);
        #pragma unroll
        for (int r = 0; r < 4; ++r) {
            const int row = q0w + quad * 4 + r;
            float x0 = s[0][r], x1 = s[1][r], x2 = s[2][r], x3 = s[3][r];
            if (masked) {
                if (kt + l15      > row) x0 = NEG_BIG;
                if (kt + 16 + l15 > row) x1 = NEG_BIG;
                if (kt + 32 + l15 > row) x2 = NEG_BIG;
                if (kt + 48 + l15 > row) x3 = NEG_BIG;
            }
            const float p0 = __expf(x0), p1 = __expf(x1);
            const float p2 = __expf(x2), p3 = __expf(x3);
            lsum[r] += (p0 + p1) + (p2 + p3);
            short* pw = &sP[wave][quad * 4 + r][l15];
            pw[0] = f2bf(p0); pw[16] = f2bf(p1); pw[32] = f2bf(p2); pw[48] = f2bf(p3);
        }
        __asm__ volatile("s_waitcnt lgkmcnt(0)" ::: "memory");
        bf16x8 pf0 = *(const bf16x8*)&sP[wave][l15][quad * 8];
        bf16x8 pf1 = *(const bf16x8*)&sP[wave][l15][32 + quad * 8];
        #pragma unroll
        for (int hc = 0; hc < 4; ++hc) {
            bf16x8 v0 = *(const bf16x8*)&sV[buf][hc * 16 + l15][bsw * 8];
            bf16x8 v1 = *(const bf16x8*)&sV[buf][hc * 16 + l15][(bsw ^ 4) * 8];
            __builtin_amdgcn_s_setprio(1);
            o_acc[hc] = MFMA16(pf0, v0, o_acc[hc]);
            o_acc[hc] = MFMA16(pf1, v1, o_acc[hc]);
            __builtin_amdgcn_s_setprio(0);
        }
        __syncthreads();   // drains stage loads for buf^1; all reads of buf done
        buf ^= 1;
    }
#undef STAGE_KV

    // write partials (slot bijective over active (by,c): by<8 -> by ; else 2by-8+c)
    const int slot = head * 24 + (by < 8 ? by : 2 * by - 8 + c);
    short* opw = op_part + ((size_t)slot * 128 + wave * 16) * 64;
    #pragma unroll
    for (int r = 0; r < 4; ++r) {
        const float l = rowsum16(lsum[r]);
        const int rloc = quad * 4 + r;
        if (l15 == 0) ls_part[slot * 128 + wave * 16 + rloc] = l;
        #pragma unroll
        for (int hc = 0; hc < 4; ++hc)
            opw[rloc * 64 + hc * 16 + l15] = f2bf(o_acc[hc][r]);
    }
}

// ---- merge partials + normalize -> Ob bf16 [b][t][n*64+h] ----
__global__ __launch_bounds__(256) void attn_reduce(
    const short* __restrict__ op_part, const float* __restrict__ ls_part,
    short* __restrict__ Ob)
{
    const int idx = blockIdx.x * 256 + threadIdx.x;   // 524288 threads
    const int r = idx >> 3;                            // row 0..65535 (head*2048+t)
    const int h0 = (idx & 7) * 8;
    const int head = r >> 11, t = r & 2047;
    const int by = t >> 7, tr = t & 127;
    const int nch = 1 + (by >= 8);
    const int base = head * 24 + (by < 8 ? by : 2 * by - 8);

    float acc[8] = {};
    float l = 0.f;
    for (int c = 0; c < nch; ++c) {
        const int slot = base + c;
        bf16x8 v = *(const bf16x8*)(op_part + ((size_t)slot * 128 + tr) * 64 + h0);
        #pragma unroll
        for (int j = 0; j < 8; ++j) acc[j] += bf2f(v[j]);
        l += ls_part[slot * 128 + tr];
    }
    const float rl = 1.0f / fmaxf(l, 1e-20f);
    bf16x8 o;
    #pragma unroll
    for (int j = 0; j < 8; ++j) o[j] = f2bf(acc[j] * rl);
    const int b = head >> 4, n = head & 15;
    *(bf16x8*)(Ob + ((size_t)(b * Tt + t)) * Dd + n * Hh + h0) = o;
}

// ======================= fallback kernels (verified R4/R5) =================
__global__ __launch_bounds__(256) void gemm_bias_split(
    const float* __restrict__ A, const float* __restrict__ Bm,
    const float* __restrict__ bias,
    float* __restrict__ dst0, float* __restrict__ dst1, float* __restrict__ dst2,
    short* __restrict__ kb, short* __restrict__ vt,
    int K, int Ncols, int Dsplit)
{
    __shared__ short sA[64][40];
    __shared__ short sBt[64][40];
    const int tid  = threadIdx.x;
    const int lane = tid & 63;
    const int wave = tid >> 6;
    const int l15  = lane & 15;
    const int quad = lane >> 4;
    const int m0 = blockIdx.x * 64;
    const int n0 = blockIdx.y * 64;
    const int wm = (wave >> 1) * 32;
    const int wn = (wave & 1) * 32;
    const int ar = tid >> 2, ac = (tid & 3) * 8;
    const int bk = tid >> 3, bc = (tid & 7) * 8;

    f32x4 acc[2][2] = {};
    for (int k0 = 0; k0 < K; k0 += 32) {
        bf16x8 av = cvt8(A  + (size_t)(m0 + ar) * K     + k0 + ac);
        bf16x8 bv = cvt8(Bm + (size_t)(k0 + bk) * Ncols + n0 + bc);
        *(bf16x8*)&sA[ar][ac] = av;
        #pragma unroll
        for (int j = 0; j < 8; ++j) sBt[bc + j][bk] = bv[j];
        __syncthreads();
        bf16x8 a0 = *(const bf16x8*)&sA[wm + l15][quad * 8];
        bf16x8 a1 = *(const bf16x8*)&sA[wm + 16 + l15][quad * 8];
        bf16x8 b0 = *(const bf16x8*)&sBt[wn + l15][quad * 8];
        bf16x8 b1 = *(const bf16x8*)&sBt[wn + 16 + l15][quad * 8];
        acc[0][0] = MFMA16(a0, b0, acc[0][0]);
        acc[0][1] = MFMA16(a0, b1, acc[0][1]);
        acc[1][0] = MFMA16(a1, b0, acc[1][0]);
        acc[1][1] = MFMA16(a1, b1, acc[1][1]);
        __syncthreads();
    }
    #pragma unroll
    for (int i = 0; i < 2; ++i)
    #pragma unroll
    for (int j = 0; j < 2; ++j) {
        const int ncol = n0 + wn + j * 16 + l15;
        const float bvf = bias[ncol];
        float* dbase; int c, which;
        if (ncol < Dsplit)        { dbase = dst0; c = ncol;            which = 0; }
        else if (ncol < 2*Dsplit) { dbase = dst1; c = ncol - Dsplit;   which = 1; }
        else                      { dbase = dst2; c = ncol - 2*Dsplit; which = 2; }
        const int nh = c >> 6, h = c & 63;
        #pragma unroll
        for (int r = 0; r < 4; ++r) {
            const int mrow = m0 + wm + i * 16 + quad * 4 + r;
            const float val = acc[i][j][r] + bvf;
            dbase[(size_t)mrow * Dsplit + c] = val;
            if (which == 1 && kb) {
                const int bidx = mrow >> 11, tt = mrow & 2047;
                kb[((size_t)(bidx * Nn + nh) * Tt + tt) * Hh + h] = f2bf(val);
            } else if (which == 2 && vt) {
                const int bidx = mrow >> 11, tt = mrow & 2047;
                vt[((size_t)(bidx * Nn + nh) * Hh + h) * Tt + tt] = f2bf(val);
            }
        }
    }
}

__global__ __launch_bounds__(256) void attn_fast(
    const float* __restrict__ Q, const short* __restrict__ Kb,
    const short* __restrict__ Vt, float* __restrict__ O)
{
    __shared__ short sP[4][2][16][40];
    const int tid  = threadIdx.x;
    const int lane = tid & 63;
    const int wave = tid >> 6;
    const int l15  = lane & 15;
    const int quad = lane >> 4;
    const int b = blockIdx.x >> 4, n = blockIdx.x & 15;
    const int qg = ((int)gridDim.y - 1 - (int)blockIdx.y) * 4 + wave;
    const int q0 = qg * 16;

    const size_t ohead  = (size_t)b * Tt * Dd + (size_t)n * Hh;
    const size_t kvhead = (size_t)(b * Nn + n) * Tt * Hh;
    const short* kbh = Kb + kvhead;
    const short* vth = Vt + kvhead;

    const float* qrow = Q + ohead + (size_t)(q0 + l15) * Dd;
    const bf16x8 qf0 = cvt8s(qrow + quad * 8, QSCALE);
    const bf16x8 qf1 = cvt8s(qrow + 32 + quad * 8, QSCALE);

    float m_i[4], l_i[4];
    f32x4 o_acc[4] = {};
    #pragma unroll
    for (int r = 0; r < 4; ++r) { m_i[r] = NEG_BIG; l_i[r] = 0.f; }

    int par = 0;
    for (int kt = 0; kt < q0 + 16; kt += 32, par ^= 1) {
        f32x4 s0 = {}, s1 = {};
        {
            const short* k0 = kbh + (size_t)(kt + l15) * Hh + quad * 8;
            bf16x8 k0a = *(const bf16x8*)k0;
            bf16x8 k0b = *(const bf16x8*)(k0 + 32);
            const short* k1 = k0 + 16 * Hh;
            bf16x8 k1a = *(const bf16x8*)k1;
            bf16x8 k1b = *(const bf16x8*)(k1 + 32);
            s0 = MFMA16(qf0, k0a, s0); s0 = MFMA16(qf1, k0b, s0);
            s1 = MFMA16(qf0, k1a, s1); s1 = MFMA16(qf1, k1b, s1);
        }
        const int qr0 = q0 + quad * 4;
        #pragma unroll
        for (int r = 0; r < 4; ++r) {
            float x0 = (kt + l15      > qr0 + r) ? NEG_BIG : s0[r];
            float x1 = (kt + 16 + l15 > qr0 + r) ? NEG_BIG : s1[r];
            const float t  = rowmax16(fmaxf(x0, x1));
            const float mn = fmaxf(m_i[r], t);
            const float alpha = __expf(m_i[r] - mn);
            const float p0 = __expf(x0 - mn);
            const float p1 = __expf(x1 - mn);
            l_i[r] = l_i[r] * alpha + rowsum16(p0 + p1);
            m_i[r] = mn;
            #pragma unroll
            for (int hc = 0; hc < 4; ++hc) o_acc[hc][r] *= alpha;
            sP[wave][par][quad * 4 + r][l15]      = f2bf(p0);
            sP[wave][par][quad * 4 + r][16 + l15] = f2bf(p1);
        }
        __asm__ volatile("s_waitcnt lgkmcnt(0)" ::: "memory");
        bf16x8 pf = *(const bf16x8*)&sP[wave][par][l15][quad * 8];
        #pragma unroll
        for (int hc = 0; hc < 4; ++hc) {
            bf16x8 vf = *(const bf16x8*)(vth + (size_t)(hc * 16 + l15) * Tt + kt + quad * 8);
            o_acc[hc] = MFMA16(pf, vf, o_acc[hc]);
        }
    }
    #pragma unroll
    for (int r = 0; r < 4; ++r) {
        const float rl = 1.0f / fmaxf(l_i[r], 1e-20f);
        #pragma unroll
        for (int hc = 0; hc < 4; ++hc)
            O[ohead + (size_t)(q0 + quad * 4 + r) * Dd + hc * 16 + l15] = o_acc[hc][r] * rl;
    }
}

extern "C" void kernel_launch(void* const* d_in, const int* in_sizes, int n_in,
                              void* d_out, int out_size, void* d_ws, size_t ws_size,
                              hipStream_t stream) {
    const float* x      = (const float*)d_in[0];
    const float* w_attn = (const float*)d_in[1];
    const float* b_attn = (const float*)d_in[2];
    const float* w_proj = (const float*)d_in[3];
    const float* b_proj = (const float*)d_in[4];

    const size_t elems = (size_t)Bb * Tt * Dd;      // 4,194,304
    float* out  = (float*)d_out;
    float* kout = out  + elems;
    float* vout = kout + elems;

    // v2 ws layout (shorts): qb, kb, vt, wpt(1M), xb(=ob after gemm1), op_part(768 slots), ls_part
    const size_t NSLOT = (size_t)32 * 24;           // 768
    const size_t need_v2 = (4 * elems + (size_t)1024 * 1024 + NSLOT * 128 * 64) * 2
                         + NSLOT * 128 * 4;         // ~48.6 MB

    if (ws_size >= need_v2) {
        short* qb  = (short*)d_ws;
        short* kb  = qb + elems;
        short* vt  = kb + elems;
        short* wpt = vt + elems;
        short* xb  = wpt + (size_t)1024 * 1024;     // dead after gemm1
        short* ob  = xb;                            // reuse for attn output
        short* op_part = xb + elems;                // 768*128*64 shorts
        float* ls_part = (float*)(op_part + NSLOT * 128 * 64);
        // wat lives where op_part starts (dead after gemm1)
        short* wat = op_part;

        prep<<<3072, 256, 0, stream>>>(x, w_attn, w_proj, xb, wat, wpt);
        gemm128<1><<<dim3(32, 24), 256, 0, stream>>>(
            xb, wat, b_attn, kout, vout, qb, kb, vt, nullptr, Dd);
        attn5<<<dim3(Bb * Nn, 16, 2), 512, 0, stream>>>(qb, kb, vt, op_part, ls_part);
        attn_reduce<<<2048, 256, 0, stream>>>(op_part, ls_part, ob);
        gemm128<2><<<dim3(32, 16), 256, 0, stream>>>(
            ob, wpt, b_proj, nullptr, nullptr, nullptr, nullptr, nullptr, out, Dd);
    } else {
        // fallback (verified R4 path): needs 32 MB ws
        float* o_ws = (float*)d_ws;
        short* kb = (short*)((char*)d_ws + elems * 4);
        short* vt = kb + elems;
        gemm_bias_split<<<dim3((Bb * Tt) / 64, (3 * Dd) / 64), 256, 0, stream>>>(
            x, w_attn, b_attn, out, kout, vout, kb, vt, Dd, 3 * Dd, Dd);
        attn_fast<<<dim3(Bb * Nn, Tt / 64), 256, 0, stream>>>(out, kb, vt, o_ws);
        gemm_bias_split<<<dim3((Bb * Tt) / 64, Dd / 64), 256, 0, stream>>>(
            o_ws, w_proj, b_proj, out, out, out, nullptr, nullptr, Dd, Dd, Dd);
    }
}

// Round 8
// 199.362 us; speedup vs baseline: 1.3772x; 1.0057x over previous
//
#include <hip/hip_runtime.h>
#include <hip/hip_bf16.h>

// I/O fp32; internal bf16 MFMA, fp32 accumulate (verified; absmax 1.6e-2).
// R8: split-kv attention (chunks of 1024), additive partials.
// R11: attn5 8-wave LDS-staged (verified, 248->215us).
// R12: counted vmcnt ring + XCD swizzle (gemm1 72->52.5us).
// R13 NULL, R14 REGRESSED (reverted), R15: MODE2 128x64 (total 200.5us).
// R16 (this round): gemm1 -> 512 threads / 8 waves, same 128x128 tile and
// 2-barrier ring. Profile: gemm1 54us with no pipe >21% busy, Occ 22%
// => latency-bound at 3 waves/SIMD (same diagnosis R11 fixed in attn).
// Wave-tile 64x32 (acc 32 VGPR), stage = 1A+1B load/thread (vmcnt(2)),
// LDS unchanged 48KB -> still 3 blocks/CU = 24 waves/CU = 6/SIMD.
// m248: 8-phase only +10% at K=1024 => occupancy, not schedule, is the lever.

typedef __attribute__((ext_vector_type(8))) short bf16x8;
typedef __attribute__((ext_vector_type(4))) float f32x4;

#define MFMA16(a, b, c) __builtin_amdgcn_mfma_f32_16x16x32_bf16(a, b, c, 0, 0, 0)

static constexpr int Bb = 2, Tt = 2048, Dd = 1024, Nn = 16, Hh = 64;
static constexpr float NEG_BIG = -30000.0f;
static constexpr float QSCALE  = 0.125f;

__device__ __forceinline__ short f2bf(float f) {
    __hip_bfloat16 h = __float2bfloat16(f);
    short s; __builtin_memcpy(&s, &h, 2); return s;
}
__device__ __forceinline__ float bf2f(short s) {
    __hip_bfloat16 h; __builtin_memcpy(&h, &s, 2); return __bfloat162float(h);
}
__device__ __forceinline__ bf16x8 cvt8(const float* __restrict__ p) {
    f32x4 a = *(const f32x4*)p, b = *(const f32x4*)(p + 4);
    bf16x8 r;
    #pragma unroll
    for (int j = 0; j < 4; ++j) { r[j] = f2bf(a[j]); r[4 + j] = f2bf(b[j]); }
    return r;
}
__device__ __forceinline__ bf16x8 cvt8s(const float* __restrict__ p, float s) {
    f32x4 a = *(const f32x4*)p, b = *(const f32x4*)(p + 4);
    bf16x8 r;
    #pragma unroll
    for (int j = 0; j < 4; ++j) { r[j] = f2bf(a[j] * s); r[4 + j] = f2bf(b[j] * s); }
    return r;
}

// async global->LDS, 16B per lane; lds base must be wave-uniform.
__device__ __forceinline__ void gload16(const short* g, short* l) {
    __builtin_amdgcn_global_load_lds(
        (const __attribute__((address_space(1))) unsigned int*)g,
        (__attribute__((address_space(3))) unsigned int*)l, 16, 0, 0);
}

template<int CTRL>
__device__ __forceinline__ float dppf(float x) {
    int i; __builtin_memcpy(&i, &x, 4);
    i = __builtin_amdgcn_update_dpp(0, i, CTRL, 0xf, 0xf, true);
    float r; __builtin_memcpy(&r, &i, 4); return r;
}
__device__ __forceinline__ float rowmax16(float x) {
    x = fmaxf(x, dppf<0x128>(x)); x = fmaxf(x, dppf<0x124>(x));
    x = fmaxf(x, dppf<0x122>(x)); x = fmaxf(x, dppf<0x121>(x));
    return x;
}
__device__ __forceinline__ float rowsum16(float x) {
    x += dppf<0x128>(x); x += dppf<0x124>(x);
    x += dppf<0x122>(x); x += dppf<0x121>(x);
    return x;
}

// ---------------- prep: x->bf16, w_attn/w_proj -> bf16 transposed [N][K] ---
__global__ __launch_bounds__(256) void prep(
    const float* __restrict__ x, const float* __restrict__ wa,
    const float* __restrict__ wp,
    short* __restrict__ xb, short* __restrict__ wat, short* __restrict__ wpt)
{
    const int bid = blockIdx.x, tid = threadIdx.x;
    if (bid < 1024) {
        __shared__ float s[64][65];
        const float* src; short* dst; int Nc, k0, n0;
        if (bid < 768) { src = wa; dst = wat; Nc = 3072; k0 = (bid & 15) * 64; n0 = (bid >> 4) * 64; }
        else { int b2 = bid - 768; src = wp; dst = wpt; Nc = 1024; k0 = (b2 & 15) * 64; n0 = (b2 >> 4) * 64; }
        const int row = tid >> 2, cg = (tid & 3) * 16;
        const float* p = src + (size_t)(k0 + row) * Nc + n0 + cg;
        #pragma unroll
        for (int i = 0; i < 4; ++i) {
            f32x4 v = *(const f32x4*)(p + 4 * i);
            #pragma unroll
            for (int j = 0; j < 4; ++j) s[row][cg + 4 * i + j] = v[j];
        }
        __syncthreads();
        bf16x8 o0, o1;
        #pragma unroll
        for (int j = 0; j < 8; ++j) { o0[j] = f2bf(s[cg + j][row]); o1[j] = f2bf(s[cg + 8 + j][row]); }
        short* q = dst + (size_t)(n0 + row) * 1024 + k0 + cg;
        *(bf16x8*)q = o0; *(bf16x8*)(q + 8) = o1;
    } else {
        const size_t base = (size_t)(bid - 1024) * 2048 + tid * 8;
        *(bf16x8*)(xb + base) = cvt8(x + base);
    }
}

// ------- 128xBN GEMM, bf16 A [M][K], bf16 Bt [N][K] -----------------------
// 3-buffer ring, stage-ahead-2, counted vmcnt, raw s_barrier, XCD supertile
// swizzle. R16: MODE1 = 512 thr / 8 waves (wave-tile 64x32, 1A+1B load per
// thread, vmcnt(2)); MODE2 = 256 thr / 4 waves, BN=64 (vmcnt(3), R15-proven).
template<int MODE>
__global__ __launch_bounds__(MODE == 1 ? 512 : 256, MODE == 1 ? 6 : 2) void gemm128(
    const short* __restrict__ A, const short* __restrict__ Bt,
    const float* __restrict__ bias,
    float* __restrict__ fk, float* __restrict__ fv,
    short* __restrict__ qb, short* __restrict__ kb, short* __restrict__ vt,
    float* __restrict__ fout, int K)
{
    constexpr int BN = (MODE == 1) ? 128 : 64;        // n-tile width
    __shared__ short sA[3][128][32];
    __shared__ short sB[3][BN][32];
    const int tid = threadIdx.x, lane = tid & 63, wave = tid >> 6;
    const int l15 = lane & 15, quad = lane >> 4;

    // XCD supertile swizzle (bijective; consecutive lids round-robin XCDs)
    const int lid = (int)blockIdx.y * (int)gridDim.x + (int)blockIdx.x;
    const int xcd = lid & 7, sidx = lid >> 3;
    constexpr int SN = (MODE == 1) ? 12 : 8;          // supertile = 8m x SN n
    const int mt = (xcd & 3) * 8 + (sidx & 7);
    const int ntl = (xcd >> 2) * SN + (sidx >> 3);
    const int m0 = mt * 128, n0 = ntl * BN;

    // wave -> output sub-tile: both modes use 64x32 wave-tiles (MF=4, NF=2)
    const int wr = (MODE == 1) ? (wave >> 2) * 64 : (wave >> 1) * 64;
    const int wc = (MODE == 1) ? (wave & 3) * 32  : (wave & 1) * 32;

    // staging source mapping: lane l covers row base+l/4, col shorts (l%4)*8
    const int rl  = lane >> 2;
    const int csh = (lane & 3) * 8;
    const size_t aOff0 = (size_t)(m0 + wave * 16 + rl) * K + csh;
    const size_t aOff1 = aOff0 + (size_t)64 * K;      // MODE2 only (4 waves x 2 rounds)
    const size_t bOff0 = (size_t)(n0 + wave * 16 + rl) * K + csh;

    f32x4 acc[4][2] = {};

#define STAGE_G(pp, kk)                                                \
    do {                                                               \
        gload16(A  + aOff0 + (kk), &sA[pp][wave * 16][0]);             \
        if constexpr (MODE == 2)                                       \
            gload16(A + aOff1 + (kk), &sA[pp][64 + wave * 16][0]);     \
        gload16(Bt + bOff0 + (kk), &sB[pp][wave * 16][0]);             \
    } while (0)

    // prologue: tiles 0 and 1 in flight (K >= 64 always here)
    STAGE_G(0, 0);
    STAGE_G(1, 32);

    int cur = 0;
    for (int k0 = 0; k0 < K; k0 += 32) {
        // tile `cur` guaranteed landed: only the NEXT tile's loads may remain
        if (k0 + 32 < K) {
            if constexpr (MODE == 1) asm volatile("s_waitcnt vmcnt(2)" ::: "memory");
            else                     asm volatile("s_waitcnt vmcnt(3)" ::: "memory");
        } else {
            asm volatile("s_waitcnt vmcnt(0)" ::: "memory");
        }
        __builtin_amdgcn_s_barrier();
        __builtin_amdgcn_sched_barrier(0);

        const int nxt2 = cur >= 1 ? cur - 1 : cur + 2;   // (cur+2)%3
        if (k0 + 64 < K) STAGE_G(nxt2, k0 + 64);

        bf16x8 af[4], bfr[2];
        #pragma unroll
        for (int mt2 = 0; mt2 < 4; ++mt2) af[mt2]  = *(const bf16x8*)&sA[cur][wr + mt2 * 16 + l15][quad * 8];
        #pragma unroll
        for (int nt2 = 0; nt2 < 2; ++nt2) bfr[nt2] = *(const bf16x8*)&sB[cur][wc + nt2 * 16 + l15][quad * 8];
        #pragma unroll
        for (int mt2 = 0; mt2 < 4; ++mt2)
        #pragma unroll
        for (int nt2 = 0; nt2 < 2; ++nt2)
            acc[mt2][nt2] = MFMA16(af[mt2], bfr[nt2], acc[mt2][nt2]);

        cur = cur < 2 ? cur + 1 : 0;
    }
#undef STAGE_G

    #pragma unroll
    for (int mt2 = 0; mt2 < 4; ++mt2)
    #pragma unroll
    for (int nt2 = 0; nt2 < 2; ++nt2) {
        const int gc = n0 + wc + nt2 * 16 + l15;
        const float bv = bias[gc];
        #pragma unroll
        for (int r = 0; r < 4; ++r) {
            const int grow = m0 + wr + mt2 * 16 + quad * 4 + r;
            const float val = acc[mt2][nt2][r] + bv;
            if (MODE == 1) {
                const int reg = gc >> 10, c = gc & 1023;
                if (reg == 0) {
                    qb[(size_t)grow * 1024 + c] = f2bf(val * QSCALE);
                } else {
                    const int bidx = grow >> 11, tt = grow & 2047;
                    const int nh = c >> 6, h = c & 63;
                    if (reg == 1) {
                        fk[(size_t)grow * 1024 + c] = val;
                        kb[((size_t)(bidx * Nn + nh) * Tt + tt) * Hh + h] = f2bf(val);
                    } else {
                        fv[(size_t)grow * 1024 + c] = val;
                        vt[((size_t)(bidx * Nn + nh) * Hh + h) * Tt + tt] = f2bf(val);
                    }
                }
            } else {
                fout[(size_t)grow * 1024 + gc] = val;
            }
        }
    }
}

// ---- attention v5: 8 waves x 16 q-rows, LDS-staged K/V (swizzled), dbuf ---
__global__ __launch_bounds__(512, 6) void attn5(
    const short* __restrict__ Qb, const short* __restrict__ Kb,
    const short* __restrict__ Vt,
    short* __restrict__ op_part, float* __restrict__ ls_part)
{
    const int by = 15 - (int)blockIdx.y;          // heavy blocks first
    const int c  = blockIdx.z;
    if (c && by < 8) return;                      // chunk 1 only for by>=8

    __shared__ short sK[2][64][64];               // [t'][h], XOR-swizzled storage
    __shared__ short sV[2][64][64];               // [h][t'], XOR-swizzled storage
    __shared__ short sP[8][16][72];

    const int tid = threadIdx.x, lane = tid & 63, wave = tid >> 6;  // 8 waves
    const int l15 = lane & 15, quad = lane >> 4;
    const int head = blockIdx.x;                  // b*16+n
    const int b = head >> 4, n = head & 15;
    const int q0w = by * 128 + wave * 16;         // this wave's 16 q-rows

    const int gmask = (q0w + 15) >> 6;            // this wave's masked-tile index
    const int g0 = c * 16;
    const int ntmax = min(16, 2 * by + 2 - g0);   // block-uniform tile count

    const size_t kvhead = (size_t)head * Tt * Hh;
    const short* kbh = Kb + kvhead;
    const short* vth = Vt + kvhead;

    // Q fragment (rows q0w..q0w+15)
    const short* qp = Qb + ((size_t)b * Tt + q0w + l15) * Dd + n * Hh + quad * 8;
    const bf16x8 qf0 = *(const bf16x8*)qp;
    const bf16x8 qf1 = *(const bf16x8*)(qp + 32);

    // staging map: wave stages rows [wave*8, wave*8+8) of each 64x64 tile.
    // storage[row][blk] holds logical[row][blk ^ (row&7)]  (blk = 16B block).
    const int sr   = wave * 8 + (lane >> 3);            // tile row
    const int srcb = (((lane & 7) ^ (lane >> 3))) * 8;  // inverse-swizzled src col (shorts)
    const int swz  = l15 & 7;
    const int bsw  = quad ^ swz;                        // storage blk for logical blk quad

    f32x4 o_acc[4] = {};
    float lsum[4] = {};

#define STAGE_KV(bb, ktb)                                               \
    do {                                                                \
        gload16(kbh + (size_t)((ktb) + sr) * Hh + srcb, &sK[bb][wave * 8][0]); \
        gload16(vth + (size_t)sr * Tt + (ktb) + srcb,   &sV[bb][wave * 8][0]); \
    } while (0)

    STAGE_KV(0, g0 * 64);
    __syncthreads();

    int buf = 0;
    for (int it = 0; it < ntmax; ++it) {
        const int kt = (g0 + it) * 64;
        if (it + 1 < ntmax) STAGE_KV(buf ^ 1, kt + 64);

        // QK^T: K fragments from swizzled LDS, j-pairs to bound VGPR
        f32x4 s[4] = {};
        #pragma unroll
        for (int jp = 0; jp < 2; ++jp) {
            bf16x8 ka0 = *(const bf16x8*)&sK[buf][32 * jp      + l15][bsw * 8];
            bf16x8 kc0 = *(const bf16x8*)&sK[buf][32 * jp      + l15][(bsw ^ 4) * 8];
            bf16x8 ka1 = *(const bf16x8*)&sK[buf][32 * jp + 16 + l15][bsw * 8];
            bf16x8 kc1 = *(const bf16x8*)&sK[buf][32 * jp + 16 + l15][(bsw ^ 4) * 8];
            __builtin_amdgcn_s_setprio(1);
            s[2 * jp]     = MFMA16(qf0, ka0, s[2 * jp]);
            s[2 * jp]     = MFMA16(qf1, kc0, s[2 * jp]);
            s[2 * jp + 1] = MFMA16(qf0, ka1, s[2 * jp + 1]);
            s[2 * jp + 1] = MFMA16(qf1, kc1, s[2 * jp + 1]);
            __builtin_amdgcn_s_setprio(0);
        }

        // softmax (fixed max; tiles past gmask fully masked -> exp = 0 exactly)
        const bool masked = (g0 + it >= gmask);
        #pragma unroll
        for (int r = 0; r < 4; ++r) {
            const int row = q0w + quad * 4 + r;
            float x0 = s[0][r], x1 = s[1][r], x2 = s[2][r], x3 = s[3][r];
            if (masked) {
                if (kt + l15      > row) x0 = NEG_BIG;
                if (kt + 16 + l15 > row) x1 = NEG_BIG;
                if (kt + 32 + l15 > row) x2 = NEG_BIG;
                if (kt + 48 + l15 > row) x3 = NEG_BIG;
            }
            const float p0 = __expf(x0), p1 = __expf(x1);
            const float p2 = __expf(x2), p3 = __expf(x3);
            lsum[r] += (p0 + p1) + (p2 + p3);
            short* pw = &sP[wave][quad * 4 + r][l15];
            pw[0] = f2bf(p0); pw[16] = f2bf(p1); pw[32] = f2bf(p2); pw[48] = f2bf(p3);
        }
        __asm__ volatile("s_waitcnt lgkmcnt(0)" ::: "memory");
        bf16x8 pf0 = *(const bf16x8*)&sP[wave][l15][quad * 8];
        bf16x8 pf1 = *(const bf16x8*)&sP[wave][l15][32 + quad * 8];
        #pragma unroll
        for (int hc = 0; hc < 4; ++hc) {
            bf16x8 v0 = *(const bf16x8*)&sV[buf][hc * 16 + l15][bsw * 8];
            bf16x8 v1 = *(const bf16x8*)&sV[buf][hc * 16 + l15][(bsw ^ 4) * 8];
            __builtin_amdgcn_s_setprio(1);
            o_acc[hc] = MFMA16(pf0, v0, o_acc[hc]);
            o_acc[hc] = MFMA16(pf1, v1, o_acc[hc]);
            __builtin_amdgcn_s_setprio(0);
        }
        __syncthreads();   // drains stage loads for buf^1; all reads of buf done
        buf ^= 1;
    }
#undef STAGE_KV

    // write partials (slot bijective over active (by,c): by<8 -> by ; else 2by-8+c)
    const int slot = head * 24 + (by < 8 ? by : 2 * by - 8 + c);
    short* opw = op_part + ((size_t)slot * 128 + wave * 16) * 64;
    #pragma unroll
    for (int r = 0; r < 4; ++r) {
        const float l = rowsum16(lsum[r]);
        const int rloc = quad * 4 + r;
        if (l15 == 0) ls_part[slot * 128 + wave * 16 + rloc] = l;
        #pragma unroll
        for (int hc = 0; hc < 4; ++hc)
            opw[rloc * 64 + hc * 16 + l15] = f2bf(o_acc[hc][r]);
    }
}

// ---- merge partials + normalize -> Ob bf16 [b][t][n*64+h] ----
__global__ __launch_bounds__(256) void attn_reduce(
    const short* __restrict__ op_part, const float* __restrict__ ls_part,
    short* __restrict__ Ob)
{
    const int idx = blockIdx.x * 256 + threadIdx.x;   // 524288 threads
    const int r = idx >> 3;                            // row 0..65535 (head*2048+t)
    const int h0 = (idx & 7) * 8;
    const int head = r >> 11, t = r & 2047;
    const int by = t >> 7, tr = t & 127;
    const int nch = 1 + (by >= 8);
    const int base = head * 24 + (by < 8 ? by : 2 * by - 8);

    float acc[8] = {};
    float l = 0.f;
    for (int c = 0; c < nch; ++c) {
        const int slot = base + c;
        bf16x8 v = *(const bf16x8*)(op_part + ((size_t)slot * 128 + tr) * 64 + h0);
        #pragma unroll
        for (int j = 0; j < 8; ++j) acc[j] += bf2f(v[j]);
        l += ls_part[slot * 128 + tr];
    }
    const float rl = 1.0f / fmaxf(l, 1e-20f);
    bf16x8 o;
    #pragma unroll
    for (int j = 0; j < 8; ++j) o[j] = f2bf(acc[j] * rl);
    const int b = head >> 4, n = head & 15;
    *(bf16x8*)(Ob + ((size_t)(b * Tt + t)) * Dd + n * Hh + h0) = o;
}

// ======================= fallback kernels (verified R4/R5) =================
__global__ __launch_bounds__(256) void gemm_bias_split(
    const float* __restrict__ A, const float* __restrict__ Bm,
    const float* __restrict__ bias,
    float* __restrict__ dst0, float* __restrict__ dst1, float* __restrict__ dst2,
    short* __restrict__ kb, short* __restrict__ vt,
    int K, int Ncols, int Dsplit)
{
    __shared__ short sA[64][40];
    __shared__ short sBt[64][40];
    const int tid  = threadIdx.x;
    const int lane = tid & 63;
    const int wave = tid >> 6;
    const int l15  = lane & 15;
    const int quad = lane >> 4;
    const int m0 = blockIdx.x * 64;
    const int n0 = blockIdx.y * 64;
    const int wm = (wave >> 1) * 32;
    const int wn = (wave & 1) * 32;
    const int ar = tid >> 2, ac = (tid & 3) * 8;
    const int bk = tid >> 3, bc = (tid & 7) * 8;

    f32x4 acc[2][2] = {};
    for (int k0 = 0; k0 < K; k0 += 32) {
        bf16x8 av = cvt8(A  + (size_t)(m0 + ar) * K     + k0 + ac);
        bf16x8 bv = cvt8(Bm + (size_t)(k0 + bk) * Ncols + n0 + bc);
        *(bf16x8*)&sA[ar][ac] = av;
        #pragma unroll
        for (int j = 0; j < 8; ++j) sBt[bc + j][bk] = bv[j];
        __syncthreads();
        bf16x8 a0 = *(const bf16x8*)&sA[wm + l15][quad * 8];
        bf16x8 a1 = *(const bf16x8*)&sA[wm + 16 + l15][quad * 8];
        bf16x8 b0 = *(const bf16x8*)&sBt[wn + l15][quad * 8];
        bf16x8 b1 = *(const bf16x8*)&sBt[wn + 16 + l15][quad * 8];
        acc[0][0] = MFMA16(a0, b0, acc[0][0]);
        acc[0][1] = MFMA16(a0, b1, acc[0][1]);
        acc[1][0] = MFMA16(a1, b0, acc[1][0]);
        acc[1][1] = MFMA16(a1, b1, acc[1][1]);
        __syncthreads();
    }
    #pragma unroll
    for (int i = 0; i < 2; ++i)
    #pragma unroll
    for (int j = 0; j < 2; ++j) {
        const int ncol = n0 + wn + j * 16 + l15;
        const float bvf = bias[ncol];
        float* dbase; int c, which;
        if (ncol < Dsplit)        { dbase = dst0; c = ncol;            which = 0; }
        else if (ncol < 2*Dsplit) { dbase = dst1; c = ncol - Dsplit;   which = 1; }
        else                      { dbase = dst2; c = ncol - 2*Dsplit; which = 2; }
        const int nh = c >> 6, h = c & 63;
        #pragma unroll
        for (int r = 0; r < 4; ++r) {
            const int mrow = m0 + wm + i * 16 + quad * 4 + r;
            const float val = acc[i][j][r] + bvf;
            dbase[(size_t)mrow * Dsplit + c] = val;
            if (which == 1 && kb) {
                const int bidx = mrow >> 11, tt = mrow & 2047;
                kb[((size_t)(bidx * Nn + nh) * Tt + tt) * Hh + h] = f2bf(val);
            } else if (which == 2 && vt) {
                const int bidx = mrow >> 11, tt = mrow & 2047;
                vt[((size_t)(bidx * Nn + nh) * Hh + h) * Tt + tt] = f2bf(val);
            }
        }
    }
}

__global__ __launch_bounds__(256) void attn_fast(
    const float* __restrict__ Q, const short* __restrict__ Kb,
    const short* __restrict__ Vt, float* __restrict__ O)
{
    __shared__ short sP[4][2][16][40];
    const int tid  = threadIdx.x;
    const int lane = tid & 63;
    const int wave = tid >> 6;
    const int l15  = lane & 15;
    const int quad = lane >> 4;
    const int b = blockIdx.x >> 4, n = blockIdx.x & 15;
    const int qg = ((int)gridDim.y - 1 - (int)blockIdx.y) * 4 + wave;
    const int q0 = qg * 16;

    const size_t ohead  = (size_t)b * Tt * Dd + (size_t)n * Hh;
    const size_t kvhead = (size_t)(b * Nn + n) * Tt * Hh;
    const short* kbh = Kb + kvhead;
    const short* vth = Vt + kvhead;

    const float* qrow = Q + ohead + (size_t)(q0 + l15) * Dd;
    const bf16x8 qf0 = cvt8s(qrow + quad * 8, QSCALE);
    const bf16x8 qf1 = cvt8s(qrow + 32 + quad * 8, QSCALE);

    float m_i[4], l_i[4];
    f32x4 o_acc[4] = {};
    #pragma unroll
    for (int r = 0; r < 4; ++r) { m_i[r] = NEG_BIG; l_i[r] = 0.f; }

    int par = 0;
    for (int kt = 0; kt < q0 + 16; kt += 32, par ^= 1) {
        f32x4 s0 = {}, s1 = {};
        {
            const short* k0 = kbh + (size_t)(kt + l15) * Hh + quad * 8;
            bf16x8 k0a = *(const bf16x8*)k0;
            bf16x8 k0b = *(const bf16x8*)(k0 + 32);
            const short* k1 = k0 + 16 * Hh;
            bf16x8 k1a = *(const bf16x8*)k1;
            bf16x8 k1b = *(const bf16x8*)(k1 + 32);
            s0 = MFMA16(qf0, k0a, s0); s0 = MFMA16(qf1, k0b, s0);
            s1 = MFMA16(qf0, k1a, s1); s1 = MFMA16(qf1, k1b, s1);
        }
        const int qr0 = q0 + quad * 4;
        #pragma unroll
        for (int r = 0; r < 4; ++r) {
            float x0 = (kt + l15      > qr0 + r) ? NEG_BIG : s0[r];
            float x1 = (kt + 16 + l15 > qr0 + r) ? NEG_BIG : s1[r];
            const float t  = rowmax16(fmaxf(x0, x1));
            const float mn = fmaxf(m_i[r], t);
            const float alpha = __expf(m_i[r] - mn);
            const float p0 = __expf(x0 - mn);
            const float p1 = __expf(x1 - mn);
            l_i[r] = l_i[r] * alpha + rowsum16(p0 + p1);
            m_i[r] = mn;
            #pragma unroll
            for (int hc = 0; hc < 4; ++hc) o_acc[hc][r] *= alpha;
            sP[wave][par][quad * 4 + r][l15]      = f2bf(p0);
            sP[wave][par][quad * 4 + r][16 + l15] = f2bf(p1);
        }
        __asm__ volatile("s_waitcnt lgkmcnt(0)" ::: "memory");
        bf16x8 pf = *(const bf16x8*)&sP[wave][par][l15][quad * 8];
        #pragma unroll
        for (int hc = 0; hc < 4; ++hc) {
            bf16x8 vf = *(const bf16x8*)(vth + (size_t)(hc * 16 + l15) * Tt + kt + quad * 8);
            o_acc[hc] = MFMA16(pf, vf, o_acc[hc]);
        }
    }
    #pragma unroll
    for (int r = 0; r < 4; ++r) {
        const float rl = 1.0f / fmaxf(l_i[r], 1e-20f);
        #pragma unroll
        for (int hc = 0; hc < 4; ++hc)
            O[ohead + (size_t)(q0 + quad * 4 + r) * Dd + hc * 16 + l15] = o_acc[hc][r] * rl;
    }
}

extern "C" void kernel_launch(void* const* d_in, const int* in_sizes, int n_in,
                              void* d_out, int out_size, void* d_ws, size_t ws_size,
                              hipStream_t stream) {
    const float* x      = (const float*)d_in[0];
    const float* w_attn = (const float*)d_in[1];
    const float* b_attn = (const float*)d_in[2];
    const float* w_proj = (const float*)d_in[3];
    const float* b_proj = (const float*)d_in[4];

    const size_t elems = (size_t)Bb * Tt * Dd;      // 4,194,304
    float* out  = (float*)d_out;
    float* kout = out  + elems;
    float* vout = kout + elems;

    // v2 ws layout (shorts): qb, kb, vt, wpt(1M), xb(=ob after gemm1), op_part(768 slots), ls_part
    const size_t NSLOT = (size_t)32 * 24;           // 768
    const size_t need_v2 = (4 * elems + (size_t)1024 * 1024 + NSLOT * 128 * 64) * 2
                         + NSLOT * 128 * 4;         // ~48.6 MB

    if (ws_size >= need_v2) {
        short* qb  = (short*)d_ws;
        short* kb  = qb + elems;
        short* vt  = kb + elems;
        short* wpt = vt + elems;
        short* xb  = wpt + (size_t)1024 * 1024;     // dead after gemm1
        short* ob  = xb;                            // reuse for attn output
        short* op_part = xb + elems;                // 768*128*64 shorts
        float* ls_part = (float*)(op_part + NSLOT * 128 * 64);
        // wat lives where op_part starts (dead after gemm1)
        short* wat = op_part;

        prep<<<3072, 256, 0, stream>>>(x, w_attn, w_proj, xb, wat, wpt);
        gemm128<1><<<dim3(32, 24), 512, 0, stream>>>(
            xb, wat, b_attn, kout, vout, qb, kb, vt, nullptr, Dd);
        attn5<<<dim3(Bb * Nn, 16, 2), 512, 0, stream>>>(qb, kb, vt, op_part, ls_part);
        attn_reduce<<<2048, 256, 0, stream>>>(op_part, ls_part, ob);
        gemm128<2><<<dim3(32, 16), 256, 0, stream>>>(
            ob, wpt, b_proj, nullptr, nullptr, nullptr, nullptr, nullptr, out, Dd);
    } else {
        // fallback (verified R4 path): needs 32 MB ws
        float* o_ws = (float*)d_ws;
        short* kb = (short*)((char*)d_ws + elems * 4);
        short* vt = kb + elems;
        gemm_bias_split<<<dim3((Bb * Tt) / 64, (3 * Dd) / 64), 256, 0, stream>>>(
            x, w_attn, b_attn, out, kout, vout, kb, vt, Dd, 3 * Dd, Dd);
        attn_fast<<<dim3(Bb * Nn, Tt / 64), 256, 0, stream>>>(out, kb, vt, o_ws);
        gemm_bias_split<<<dim3((Bb * Tt) / 64, Dd / 64), 256, 0, stream>>>(
            o_ws, w_proj, b_proj, out, out, out, nullptr, nullptr, Dd, Dd, Dd);
    }
}

// Round 9
// 196.449 us; speedup vs baseline: 1.3977x; 1.0148x over previous
//
#include <hip/hip_runtime.h>
#include <hip/hip_bf16.h>

// I/O fp32; internal bf16 MFMA, fp32 accumulate (verified; absmax 1.6e-2).
// R8: split-kv attention (chunks of 1024), additive partials.
// R11: attn5 8-wave LDS-staged. R12: counted vmcnt ring + XCD swizzle.
// R13 NULL, R14 REGRESSED (reverted), R15/R16: tiles+occupancy (199.4us;
// gemm1 pinned 51-54 across 3 structures & 2 occupancies => local ceiling).
// R17 (this round): harvest the un-profiled tail with proven-template
// parameter changes only:
//  - gemm2: 64x64 tiles, grid 64x16=1024 blocks = 4 blocks/CU (was 2/CU),
//    uniform 2-load staging -> vmcnt(2), wave-tile 32x32.
//  - attn5: by<8 blocks (single chunk) write normalized output DIRECTLY
//    (rowsum16 is lane-uniform: row_ror butterfly); skips bf16 round-trip.
//  - attn_reduce: only t>=1024 rows (half the work, 1024 blocks).

typedef __attribute__((ext_vector_type(8))) short bf16x8;
typedef __attribute__((ext_vector_type(4))) float f32x4;

#define MFMA16(a, b, c) __builtin_amdgcn_mfma_f32_16x16x32_bf16(a, b, c, 0, 0, 0)

static constexpr int Bb = 2, Tt = 2048, Dd = 1024, Nn = 16, Hh = 64;
static constexpr float NEG_BIG = -30000.0f;
static constexpr float QSCALE  = 0.125f;

__device__ __forceinline__ short f2bf(float f) {
    __hip_bfloat16 h = __float2bfloat16(f);
    short s; __builtin_memcpy(&s, &h, 2); return s;
}
__device__ __forceinline__ float bf2f(short s) {
    __hip_bfloat16 h; __builtin_memcpy(&h, &s, 2); return __bfloat162float(h);
}
__device__ __forceinline__ bf16x8 cvt8(const float* __restrict__ p) {
    f32x4 a = *(const f32x4*)p, b = *(const f32x4*)(p + 4);
    bf16x8 r;
    #pragma unroll
    for (int j = 0; j < 4; ++j) { r[j] = f2bf(a[j]); r[4 + j] = f2bf(b[j]); }
    return r;
}
__device__ __forceinline__ bf16x8 cvt8s(const float* __restrict__ p, float s) {
    f32x4 a = *(const f32x4*)p, b = *(const f32x4*)(p + 4);
    bf16x8 r;
    #pragma unroll
    for (int j = 0; j < 4; ++j) { r[j] = f2bf(a[j] * s); r[4 + j] = f2bf(b[j] * s); }
    return r;
}

// async global->LDS, 16B per lane; lds base must be wave-uniform.
__device__ __forceinline__ void gload16(const short* g, short* l) {
    __builtin_amdgcn_global_load_lds(
        (const __attribute__((address_space(1))) unsigned int*)g,
        (__attribute__((address_space(3))) unsigned int*)l, 16, 0, 0);
}

template<int CTRL>
__device__ __forceinline__ float dppf(float x) {
    int i; __builtin_memcpy(&i, &x, 4);
    i = __builtin_amdgcn_update_dpp(0, i, CTRL, 0xf, 0xf, true);
    float r; __builtin_memcpy(&r, &i, 4); return r;
}
__device__ __forceinline__ float rowmax16(float x) {
    x = fmaxf(x, dppf<0x128>(x)); x = fmaxf(x, dppf<0x124>(x));
    x = fmaxf(x, dppf<0x122>(x)); x = fmaxf(x, dppf<0x121>(x));
    return x;
}
__device__ __forceinline__ float rowsum16(float x) {
    x += dppf<0x128>(x); x += dppf<0x124>(x);
    x += dppf<0x122>(x); x += dppf<0x121>(x);
    return x;
}

// ---------------- prep: x->bf16, w_attn/w_proj -> bf16 transposed [N][K] ---
__global__ __launch_bounds__(256) void prep(
    const float* __restrict__ x, const float* __restrict__ wa,
    const float* __restrict__ wp,
    short* __restrict__ xb, short* __restrict__ wat, short* __restrict__ wpt)
{
    const int bid = blockIdx.x, tid = threadIdx.x;
    if (bid < 1024) {
        __shared__ float s[64][65];
        const float* src; short* dst; int Nc, k0, n0;
        if (bid < 768) { src = wa; dst = wat; Nc = 3072; k0 = (bid & 15) * 64; n0 = (bid >> 4) * 64; }
        else { int b2 = bid - 768; src = wp; dst = wpt; Nc = 1024; k0 = (b2 & 15) * 64; n0 = (b2 >> 4) * 64; }
        const int row = tid >> 2, cg = (tid & 3) * 16;
        const float* p = src + (size_t)(k0 + row) * Nc + n0 + cg;
        #pragma unroll
        for (int i = 0; i < 4; ++i) {
            f32x4 v = *(const f32x4*)(p + 4 * i);
            #pragma unroll
            for (int j = 0; j < 4; ++j) s[row][cg + 4 * i + j] = v[j];
        }
        __syncthreads();
        bf16x8 o0, o1;
        #pragma unroll
        for (int j = 0; j < 8; ++j) { o0[j] = f2bf(s[cg + j][row]); o1[j] = f2bf(s[cg + 8 + j][row]); }
        short* q = dst + (size_t)(n0 + row) * 1024 + k0 + cg;
        *(bf16x8*)q = o0; *(bf16x8*)(q + 8) = o1;
    } else {
        const size_t base = (size_t)(bid - 1024) * 2048 + tid * 8;
        *(bf16x8*)(xb + base) = cvt8(x + base);
    }
}

// ------- BMxBN GEMM, bf16 A [M][K], bf16 Bt [N][K] ------------------------
// 3-buffer ring, stage-ahead-2, counted vmcnt(2), raw s_barrier, XCD
// supertile swizzle. MODE1: 128x128, 512 thr (wave-tile 64x32).
// MODE2: 64x64, 256 thr (wave-tile 32x32), grid 64x16 = 4 blocks/CU.
// Both: 1 A-load + 1 B-load per thread per K-step.
template<int MODE>
__global__ __launch_bounds__(MODE == 1 ? 512 : 256, MODE == 1 ? 6 : 4) void gemm128(
    const short* __restrict__ A, const short* __restrict__ Bt,
    const float* __restrict__ bias,
    float* __restrict__ fk, float* __restrict__ fv,
    short* __restrict__ qb, short* __restrict__ kb, short* __restrict__ vt,
    float* __restrict__ fout, int K)
{
    constexpr int BM = (MODE == 1) ? 128 : 64;
    constexpr int BN = (MODE == 1) ? 128 : 64;
    constexpr int MF = (MODE == 1) ? 4 : 2;           // m-frags per wave
    __shared__ short sA[3][BM][32];
    __shared__ short sB[3][BN][32];
    const int tid = threadIdx.x, lane = tid & 63, wave = tid >> 6;
    const int l15 = lane & 15, quad = lane >> 4;

    // XCD supertile swizzle (bijective; consecutive lids round-robin XCDs)
    const int lid = (int)blockIdx.y * (int)gridDim.x + (int)blockIdx.x;
    const int xcd = lid & 7, sidx = lid >> 3;
    int mt, ntl;
    if constexpr (MODE == 1) { mt = (xcd & 3) * 8  + (sidx & 7);  ntl = (xcd >> 2) * 12 + (sidx >> 3); }
    else                     { mt = (xcd & 3) * 16 + (sidx & 15); ntl = (xcd >> 2) * 8  + (sidx >> 4); }
    const int m0 = mt * BM, n0 = ntl * BN;

    // wave -> output sub-tile
    const int wr = (MODE == 1) ? (wave >> 2) * 64 : (wave >> 1) * 32;
    const int wc = (MODE == 1) ? (wave & 3) * 32  : (wave & 1) * 32;

    // staging: wave covers rows [wave*16, +16) of A and of B
    const int rl  = lane >> 2;
    const int csh = (lane & 3) * 8;
    const size_t aOff0 = (size_t)(m0 + wave * 16 + rl) * K + csh;
    const size_t bOff0 = (size_t)(n0 + wave * 16 + rl) * K + csh;

    f32x4 acc[MF][2] = {};

#define STAGE_G(pp, kk)                                                \
    do {                                                               \
        gload16(A  + aOff0 + (kk), &sA[pp][wave * 16][0]);             \
        gload16(Bt + bOff0 + (kk), &sB[pp][wave * 16][0]);             \
    } while (0)

    // prologue: tiles 0 and 1 in flight (K >= 64 always here)
    STAGE_G(0, 0);
    STAGE_G(1, 32);

    int cur = 0;
    for (int k0 = 0; k0 < K; k0 += 32) {
        // tile `cur` guaranteed landed: only the NEXT tile's loads may remain
        if (k0 + 32 < K) {
            asm volatile("s_waitcnt vmcnt(2)" ::: "memory");
        } else {
            asm volatile("s_waitcnt vmcnt(0)" ::: "memory");
        }
        __builtin_amdgcn_s_barrier();
        __builtin_amdgcn_sched_barrier(0);

        const int nxt2 = cur >= 1 ? cur - 1 : cur + 2;   // (cur+2)%3
        if (k0 + 64 < K) STAGE_G(nxt2, k0 + 64);

        bf16x8 af[MF], bfr[2];
        #pragma unroll
        for (int mt2 = 0; mt2 < MF; ++mt2) af[mt2]  = *(const bf16x8*)&sA[cur][wr + mt2 * 16 + l15][quad * 8];
        #pragma unroll
        for (int nt2 = 0; nt2 < 2; ++nt2)  bfr[nt2] = *(const bf16x8*)&sB[cur][wc + nt2 * 16 + l15][quad * 8];
        #pragma unroll
        for (int mt2 = 0; mt2 < MF; ++mt2)
        #pragma unroll
        for (int nt2 = 0; nt2 < 2; ++nt2)
            acc[mt2][nt2] = MFMA16(af[mt2], bfr[nt2], acc[mt2][nt2]);

        cur = cur < 2 ? cur + 1 : 0;
    }
#undef STAGE_G

    #pragma unroll
    for (int mt2 = 0; mt2 < MF; ++mt2)
    #pragma unroll
    for (int nt2 = 0; nt2 < 2; ++nt2) {
        const int gc = n0 + wc + nt2 * 16 + l15;
        const float bv = bias[gc];
        #pragma unroll
        for (int r = 0; r < 4; ++r) {
            const int grow = m0 + wr + mt2 * 16 + quad * 4 + r;
            const float val = acc[mt2][nt2][r] + bv;
            if (MODE == 1) {
                const int reg = gc >> 10, c = gc & 1023;
                if (reg == 0) {
                    qb[(size_t)grow * 1024 + c] = f2bf(val * QSCALE);
                } else {
                    const int bidx = grow >> 11, tt = grow & 2047;
                    const int nh = c >> 6, h = c & 63;
                    if (reg == 1) {
                        fk[(size_t)grow * 1024 + c] = val;
                        kb[((size_t)(bidx * Nn + nh) * Tt + tt) * Hh + h] = f2bf(val);
                    } else {
                        fv[(size_t)grow * 1024 + c] = val;
                        vt[((size_t)(bidx * Nn + nh) * Hh + h) * Tt + tt] = f2bf(val);
                    }
                }
            } else {
                fout[(size_t)grow * 1024 + gc] = val;
            }
        }
    }
}

// ---- attention v5: 8 waves x 16 q-rows, LDS-staged K/V (swizzled), dbuf ---
// R17: by<8 (single chunk) writes normalized output directly to Ob.
__global__ __launch_bounds__(512, 6) void attn5(
    const short* __restrict__ Qb, const short* __restrict__ Kb,
    const short* __restrict__ Vt,
    short* __restrict__ op_part, float* __restrict__ ls_part,
    short* __restrict__ Ob)
{
    const int by = 15 - (int)blockIdx.y;          // heavy blocks first
    const int c  = blockIdx.z;
    if (c && by < 8) return;                      // chunk 1 only for by>=8

    __shared__ short sK[2][64][64];               // [t'][h], XOR-swizzled storage
    __shared__ short sV[2][64][64];               // [h][t'], XOR-swizzled storage
    __shared__ short sP[8][16][72];

    const int tid = threadIdx.x, lane = tid & 63, wave = tid >> 6;  // 8 waves
    const int l15 = lane & 15, quad = lane >> 4;
    const int head = blockIdx.x;                  // b*16+n
    const int b = head >> 4, n = head & 15;
    const int q0w = by * 128 + wave * 16;         // this wave's 16 q-rows

    const int gmask = (q0w + 15) >> 6;            // this wave's masked-tile index
    const int g0 = c * 16;
    const int ntmax = min(16, 2 * by + 2 - g0);   // block-uniform tile count

    const size_t kvhead = (size_t)head * Tt * Hh;
    const short* kbh = Kb + kvhead;
    const short* vth = Vt + kvhead;

    // Q fragment (rows q0w..q0w+15)
    const short* qp = Qb + ((size_t)b * Tt + q0w + l15) * Dd + n * Hh + quad * 8;
    const bf16x8 qf0 = *(const bf16x8*)qp;
    const bf16x8 qf1 = *(const bf16x8*)(qp + 32);

    // staging map: wave stages rows [wave*8, wave*8+8) of each 64x64 tile.
    // storage[row][blk] holds logical[row][blk ^ (row&7)]  (blk = 16B block).
    const int sr   = wave * 8 + (lane >> 3);            // tile row
    const int srcb = (((lane & 7) ^ (lane >> 3))) * 8;  // inverse-swizzled src col (shorts)
    const int swz  = l15 & 7;
    const int bsw  = quad ^ swz;                        // storage blk for logical blk quad

    f32x4 o_acc[4] = {};
    float lsum[4] = {};

#define STAGE_KV(bb, ktb)                                               \
    do {                                                                \
        gload16(kbh + (size_t)((ktb) + sr) * Hh + srcb, &sK[bb][wave * 8][0]); \
        gload16(vth + (size_t)sr * Tt + (ktb) + srcb,   &sV[bb][wave * 8][0]); \
    } while (0)

    STAGE_KV(0, g0 * 64);
    __syncthreads();

    int buf = 0;
    for (int it = 0; it < ntmax; ++it) {
        const int kt = (g0 + it) * 64;
        if (it + 1 < ntmax) STAGE_KV(buf ^ 1, kt + 64);

        // QK^T: K fragments from swizzled LDS, j-pairs to bound VGPR
        f32x4 s[4] = {};
        #pragma unroll
        for (int jp = 0; jp < 2; ++jp) {
            bf16x8 ka0 = *(const bf16x8*)&sK[buf][32 * jp      + l15][bsw * 8];
            bf16x8 kc0 = *(const bf16x8*)&sK[buf][32 * jp      + l15][(bsw ^ 4) * 8];
            bf16x8 ka1 = *(const bf16x8*)&sK[buf][32 * jp + 16 + l15][bsw * 8];
            bf16x8 kc1 = *(const bf16x8*)&sK[buf][32 * jp + 16 + l15][(bsw ^ 4) * 8];
            __builtin_amdgcn_s_setprio(1);
            s[2 * jp]     = MFMA16(qf0, ka0, s[2 * jp]);
            s[2 * jp]     = MFMA16(qf1, kc0, s[2 * jp]);
            s[2 * jp + 1] = MFMA16(qf0, ka1, s[2 * jp + 1]);
            s[2 * jp + 1] = MFMA16(qf1, kc1, s[2 * jp + 1]);
            __builtin_amdgcn_s_setprio(0);
        }

        // softmax (fixed max; tiles past gmask fully masked -> exp = 0 exactly)
        const bool masked = (g0 + it >= gmask);
        #pragma unroll
        for (int r = 0; r < 4; ++r) {
            const int row = q0w + quad * 4 + r;
            float x0 = s[0][r], x1 = s[1][r], x2 = s[2][r], x3 = s[3][r];
            if (masked) {
                if (kt + l15      > row) x0 = NEG_BIG;
                if (kt + 16 + l15 > row) x1 = NEG_BIG;
                if (kt + 32 + l15 > row) x2 = NEG_BIG;
                if (kt + 48 + l15 > row) x3 = NEG_BIG;
            }
            const float p0 = __expf(x0), p1 = __expf(x1);
            const float p2 = __expf(x2), p3 = __expf(x3);
            lsum[r] += (p0 + p1) + (p2 + p3);
            short* pw = &sP[wave][quad * 4 + r][l15];
            pw[0] = f2bf(p0); pw[16] = f2bf(p1); pw[32] = f2bf(p2); pw[48] = f2bf(p3);
        }
        __asm__ volatile("s_waitcnt lgkmcnt(0)" ::: "memory");
        bf16x8 pf0 = *(const bf16x8*)&sP[wave][l15][quad * 8];
        bf16x8 pf1 = *(const bf16x8*)&sP[wave][l15][32 + quad * 8];
        #pragma unroll
        for (int hc = 0; hc < 4; ++hc) {
            bf16x8 v0 = *(const bf16x8*)&sV[buf][hc * 16 + l15][bsw * 8];
            bf16x8 v1 = *(const bf16x8*)&sV[buf][hc * 16 + l15][(bsw ^ 4) * 8];
            __builtin_amdgcn_s_setprio(1);
            o_acc[hc] = MFMA16(pf0, v0, o_acc[hc]);
            o_acc[hc] = MFMA16(pf1, v1, o_acc[hc]);
            __builtin_amdgcn_s_setprio(0);
        }
        __syncthreads();   // drains stage loads for buf^1; all reads of buf done
        buf ^= 1;
    }
#undef STAGE_KV

    if (by < 8) {
        // single chunk: normalize and write final output directly
        short* obw = Ob + ((size_t)b * Tt + q0w) * Dd + n * Hh;
        #pragma unroll
        for (int r = 0; r < 4; ++r) {
            const float rlv = 1.0f / fmaxf(rowsum16(lsum[r]), 1e-20f);
            const int rloc = quad * 4 + r;
            #pragma unroll
            for (int hc = 0; hc < 4; ++hc)
                obw[(size_t)rloc * Dd + hc * 16 + l15] = f2bf(o_acc[hc][r] * rlv);
        }
    } else {
        // two chunks: write partials (slot = head*24 + 2by-8+c, bijective)
        const int slot = head * 24 + 2 * by - 8 + c;
        short* opw = op_part + ((size_t)slot * 128 + wave * 16) * 64;
        #pragma unroll
        for (int r = 0; r < 4; ++r) {
            const float l = rowsum16(lsum[r]);
            const int rloc = quad * 4 + r;
            if (l15 == 0) ls_part[slot * 128 + wave * 16 + rloc] = l;
            #pragma unroll
            for (int hc = 0; hc < 4; ++hc)
                opw[rloc * 64 + hc * 16 + l15] = f2bf(o_acc[hc][r]);
        }
    }
}

// ---- merge partials + normalize -> Ob bf16, rows t>=1024 only ----
__global__ __launch_bounds__(256) void attn_reduce(
    const short* __restrict__ op_part, const float* __restrict__ ls_part,
    short* __restrict__ Ob)
{
    const int idx = blockIdx.x * 256 + threadIdx.x;   // 262144 threads
    const int r = idx >> 3;                            // 0..32767 (head*1024 + t-1024)
    const int h0 = (idx & 7) * 8;
    const int head = r >> 10, t = 1024 + (r & 1023);
    const int by = t >> 7, tr = t & 127;               // by in 8..15
    const int base = head * 24 + 2 * by - 8;

    float acc[8] = {};
    float l = 0.f;
    #pragma unroll
    for (int c = 0; c < 2; ++c) {
        const int slot = base + c;
        bf16x8 v = *(const bf16x8*)(op_part + ((size_t)slot * 128 + tr) * 64 + h0);
        #pragma unroll
        for (int j = 0; j < 8; ++j) acc[j] += bf2f(v[j]);
        l += ls_part[slot * 128 + tr];
    }
    const float rl = 1.0f / fmaxf(l, 1e-20f);
    bf16x8 o;
    #pragma unroll
    for (int j = 0; j < 8; ++j) o[j] = f2bf(acc[j] * rl);
    const int b = head >> 4, n = head & 15;
    *(bf16x8*)(Ob + ((size_t)(b * Tt + t)) * Dd + n * Hh + h0) = o;
}

// ======================= fallback kernels (verified R4/R5) =================
__global__ __launch_bounds__(256) void gemm_bias_split(
    const float* __restrict__ A, const float* __restrict__ Bm,
    const float* __restrict__ bias,
    float* __restrict__ dst0, float* __restrict__ dst1, float* __restrict__ dst2,
    short* __restrict__ kb, short* __restrict__ vt,
    int K, int Ncols, int Dsplit)
{
    __shared__ short sA[64][40];
    __shared__ short sBt[64][40];
    const int tid  = threadIdx.x;
    const int lane = tid & 63;
    const int wave = tid >> 6;
    const int l15  = lane & 15;
    const int quad = lane >> 4;
    const int m0 = blockIdx.x * 64;
    const int n0 = blockIdx.y * 64;
    const int wm = (wave >> 1) * 32;
    const int wn = (wave & 1) * 32;
    const int ar = tid >> 2, ac = (tid & 3) * 8;
    const int bk = tid >> 3, bc = (tid & 7) * 8;

    f32x4 acc[2][2] = {};
    for (int k0 = 0; k0 < K; k0 += 32) {
        bf16x8 av = cvt8(A  + (size_t)(m0 + ar) * K     + k0 + ac);
        bf16x8 bv = cvt8(Bm + (size_t)(k0 + bk) * Ncols + n0 + bc);
        *(bf16x8*)&sA[ar][ac] = av;
        #pragma unroll
        for (int j = 0; j < 8; ++j) sBt[bc + j][bk] = bv[j];
        __syncthreads();
        bf16x8 a0 = *(const bf16x8*)&sA[wm + l15][quad * 8];
        bf16x8 a1 = *(const bf16x8*)&sA[wm + 16 + l15][quad * 8];
        bf16x8 b0 = *(const bf16x8*)&sBt[wn + l15][quad * 8];
        bf16x8 b1 = *(const bf16x8*)&sBt[wn + 16 + l15][quad * 8];
        acc[0][0] = MFMA16(a0, b0, acc[0][0]);
        acc[0][1] = MFMA16(a0, b1, acc[0][1]);
        acc[1][0] = MFMA16(a1, b0, acc[1][0]);
        acc[1][1] = MFMA16(a1, b1, acc[1][1]);
        __syncthreads();
    }
    #pragma unroll
    for (int i = 0; i < 2; ++i)
    #pragma unroll
    for (int j = 0; j < 2; ++j) {
        const int ncol = n0 + wn + j * 16 + l15;
        const float bvf = bias[ncol];
        float* dbase; int c, which;
        if (ncol < Dsplit)        { dbase = dst0; c = ncol;            which = 0; }
        else if (ncol < 2*Dsplit) { dbase = dst1; c = ncol - Dsplit;   which = 1; }
        else                      { dbase = dst2; c = ncol - 2*Dsplit; which = 2; }
        const int nh = c >> 6, h = c & 63;
        #pragma unroll
        for (int r = 0; r < 4; ++r) {
            const int mrow = m0 + wm + i * 16 + quad * 4 + r;
            const float val = acc[i][j][r] + bvf;
            dbase[(size_t)mrow * Dsplit + c] = val;
            if (which == 1 && kb) {
                const int bidx = mrow >> 11, tt = mrow & 2047;
                kb[((size_t)(bidx * Nn + nh) * Tt + tt) * Hh + h] = f2bf(val);
            } else if (which == 2 && vt) {
                const int bidx = mrow >> 11, tt = mrow & 2047;
                vt[((size_t)(bidx * Nn + nh) * Hh + h) * Tt + tt] = f2bf(val);
            }
        }
    }
}

__global__ __launch_bounds__(256) void attn_fast(
    const float* __restrict__ Q, const short* __restrict__ Kb,
    const short* __restrict__ Vt, float* __restrict__ O)
{
    __shared__ short sP[4][2][16][40];
    const int tid  = threadIdx.x;
    const int lane = tid & 63;
    const int wave = tid >> 6;
    const int l15  = lane & 15;
    const int quad = lane >> 4;
    const int b = blockIdx.x >> 4, n = blockIdx.x & 15;
    const int qg = ((int)gridDim.y - 1 - (int)blockIdx.y) * 4 + wave;
    const int q0 = qg * 16;

    const size_t ohead  = (size_t)b * Tt * Dd + (size_t)n * Hh;
    const size_t kvhead = (size_t)(b * Nn + n) * Tt * Hh;
    const short* kbh = Kb + kvhead;
    const short* vth = Vt + kvhead;

    const float* qrow = Q + ohead + (size_t)(q0 + l15) * Dd;
    const bf16x8 qf0 = cvt8s(qrow + quad * 8, QSCALE);
    const bf16x8 qf1 = cvt8s(qrow + 32 + quad * 8, QSCALE);

    float m_i[4], l_i[4];
    f32x4 o_acc[4] = {};
    #pragma unroll
    for (int r = 0; r < 4; ++r) { m_i[r] = NEG_BIG; l_i[r] = 0.f; }

    int par = 0;
    for (int kt = 0; kt < q0 + 16; kt += 32, par ^= 1) {
        f32x4 s0 = {}, s1 = {};
        {
            const short* k0 = kbh + (size_t)(kt + l15) * Hh + quad * 8;
            bf16x8 k0a = *(const bf16x8*)k0;
            bf16x8 k0b = *(const bf16x8*)(k0 + 32);
            const short* k1 = k0 + 16 * Hh;
            bf16x8 k1a = *(const bf16x8*)k1;
            bf16x8 k1b = *(const bf16x8*)(k1 + 32);
            s0 = MFMA16(qf0, k0a, s0); s0 = MFMA16(qf1, k0b, s0);
            s1 = MFMA16(qf0, k1a, s1); s1 = MFMA16(qf1, k1b, s1);
        }
        const int qr0 = q0 + quad * 4;
        #pragma unroll
        for (int r = 0; r < 4; ++r) {
            float x0 = (kt + l15      > qr0 + r) ? NEG_BIG : s0[r];
            float x1 = (kt + 16 + l15 > qr0 + r) ? NEG_BIG : s1[r];
            const float t  = rowmax16(fmaxf(x0, x1));
            const float mn = fmaxf(m_i[r], t);
            const float alpha = __expf(m_i[r] - mn);
            const float p0 = __expf(x0 - mn);
            const float p1 = __expf(x1 - mn);
            l_i[r] = l_i[r] * alpha + rowsum16(p0 + p1);
            m_i[r] = mn;
            #pragma unroll
            for (int hc = 0; hc < 4; ++hc) o_acc[hc][r] *= alpha;
            sP[wave][par][quad * 4 + r][l15]      = f2bf(p0);
            sP[wave][par][quad * 4 + r][16 + l15] = f2bf(p1);
        }
        __asm__ volatile("s_waitcnt lgkmcnt(0)" ::: "memory");
        bf16x8 pf = *(const bf16x8*)&sP[wave][par][l15][quad * 8];
        #pragma unroll
        for (int hc = 0; hc < 4; ++hc) {
            bf16x8 vf = *(const bf16x8*)(vth + (size_t)(hc * 16 + l15) * Tt + kt + quad * 8);
            o_acc[hc] = MFMA16(pf, vf, o_acc[hc]);
        }
    }
    #pragma unroll
    for (int r = 0; r < 4; ++r) {
        const float rl = 1.0f / fmaxf(l_i[r], 1e-20f);
        #pragma unroll
        for (int hc = 0; hc < 4; ++hc)
            O[ohead + (size_t)(q0 + quad * 4 + r) * Dd + hc * 16 + l15] = o_acc[hc][r] * rl;
    }
}

extern "C" void kernel_launch(void* const* d_in, const int* in_sizes, int n_in,
                              void* d_out, int out_size, void* d_ws, size_t ws_size,
                              hipStream_t stream) {
    const float* x      = (const float*)d_in[0];
    const float* w_attn = (const float*)d_in[1];
    const float* b_attn = (const float*)d_in[2];
    const float* w_proj = (const float*)d_in[3];
    const float* b_proj = (const float*)d_in[4];

    const size_t elems = (size_t)Bb * Tt * Dd;      // 4,194,304
    float* out  = (float*)d_out;
    float* kout = out  + elems;
    float* vout = kout + elems;

    // v2 ws layout (shorts): qb, kb, vt, wpt(1M), xb(=ob after gemm1), op_part(768 slots), ls_part
    const size_t NSLOT = (size_t)32 * 24;           // 768
    const size_t need_v2 = (4 * elems + (size_t)1024 * 1024 + NSLOT * 128 * 64) * 2
                         + NSLOT * 128 * 4;         // ~48.6 MB

    if (ws_size >= need_v2) {
        short* qb  = (short*)d_ws;
        short* kb  = qb + elems;
        short* vt  = kb + elems;
        short* wpt = vt + elems;
        short* xb  = wpt + (size_t)1024 * 1024;     // dead after gemm1
        short* ob  = xb;                            // reuse for attn output
        short* op_part = xb + elems;                // 768*128*64 shorts
        float* ls_part = (float*)(op_part + NSLOT * 128 * 64);
        // wat lives where op_part starts (dead after gemm1)
        short* wat = op_part;

        prep<<<3072, 256, 0, stream>>>(x, w_attn, w_proj, xb, wat, wpt);
        gemm128<1><<<dim3(32, 24), 512, 0, stream>>>(
            xb, wat, b_attn, kout, vout, qb, kb, vt, nullptr, Dd);
        attn5<<<dim3(Bb * Nn, 16, 2), 512, 0, stream>>>(qb, kb, vt, op_part, ls_part, ob);
        attn_reduce<<<1024, 256, 0, stream>>>(op_part, ls_part, ob);
        gemm128<2><<<dim3(64, 16), 256, 0, stream>>>(
            ob, wpt, b_proj, nullptr, nullptr, nullptr, nullptr, nullptr, out, Dd);
    } else {
        // fallback (verified R4 path): needs 32 MB ws
        float* o_ws = (float*)d_ws;
        short* kb = (short*)((char*)d_ws + elems * 4);
        short* vt = kb + elems;
        gemm_bias_split<<<dim3((Bb * Tt) / 64, (3 * Dd) / 64), 256, 0, stream>>>(
            x, w_attn, b_attn, out, kout, vout, kb, vt, Dd, 3 * Dd, Dd);
        attn_fast<<<dim3(Bb * Nn, Tt / 64), 256, 0, stream>>>(out, kb, vt, o_ws);
        gemm_bias_split<<<dim3((Bb * Tt) / 64, Dd / 64), 256, 0, stream>>>(
            o_ws, w_proj, b_proj, out, out, out, nullptr, nullptr, Dd, Dd, Dd);
    }
}